// Round 9
// baseline (1634.876 us; speedup 1.0000x reference)
//
#include <hip/hip_runtime.h>
#include <stdint.h>

#define NFEAT 500
#define KPAD  512
#define NHID  256
#define NCLS  40
#define NCPAD 48
#define NLAY  5
#define BSH   8      // coarse bucket = row >> 8
#define CHUNK 8192   // edges per kA block

typedef __attribute__((ext_vector_type(8))) short short8;
typedef __attribute__((ext_vector_type(4))) float f32x4;
typedef __attribute__((ext_vector_type(2))) float f32x2;

__device__ __forceinline__ ushort f2bf(float f) {
  uint32_t u = __float_as_uint(f);
  u += 0x7fffu + ((u >> 16) & 1u);
  return (ushort)(u >> 16);
}
__device__ __forceinline__ float b2f(ushort h) {
  return __uint_as_float(((uint32_t)h) << 16);
}

// ---------------- casts (fp32 -> bf16, with K padding) — weights only ----------------
__global__ __launch_bounds__(256) void k_cast_pad(const float* __restrict__ src,
    ushort* __restrict__ dst, int rows, int scol, int dcol) {
  int id = blockIdx.x * 256 + threadIdx.x;
  int cpr = dcol >> 2;
  if (id >= rows * cpr) return;
  int r = id / cpr;
  int c = (id % cpr) * 4;
  float4 v;
  if (c + 3 < scol) {
    v = *(const float4*)(src + (size_t)r * scol + c);
  } else {
    v.x = (c + 0 < scol) ? src[(size_t)r * scol + c + 0] : 0.f;
    v.y = (c + 1 < scol) ? src[(size_t)r * scol + c + 1] : 0.f;
    v.z = (c + 2 < scol) ? src[(size_t)r * scol + c + 2] : 0.f;
    v.w = (c + 3 < scol) ? src[(size_t)r * scol + c + 3] : 0.f;
  }
  ushort4 o;
  o.x = f2bf(v.x); o.y = f2bf(v.y); o.z = f2bf(v.z); o.w = f2bf(v.w);
  *(ushort4*)(dst + (size_t)r * dcol + c) = o;
}

// ---------------- CSR build, phase A: coarse bucket scatter ----------------
__global__ __launch_bounds__(256) void kA_scatter(const int* __restrict__ row,
    const int* __restrict__ col, const float* __restrict__ val,
    int* __restrict__ ccur, int2* __restrict__ pb, int E, int P, int CAP) {
  __shared__ int lh[512];
  const int t = threadIdx.x;
  const int b0 = blockIdx.x * CHUNK;
  for (int i = t; i < P; i += 256) lh[i] = 0;
  __syncthreads();
#pragma unroll 4
  for (int i = 0; i < CHUNK / 256; i++) {
    int idx = b0 + i * 256 + t;
    if (idx < E) atomicAdd(&lh[row[idx] >> BSH], 1);
  }
  __syncthreads();
  for (int i = t; i < P; i += 256) {
    int c = lh[i];
    lh[i] = (c > 0) ? atomicAdd(&ccur[i], c) : 0;
  }
  __syncthreads();
#pragma unroll 4
  for (int i = 0; i < CHUNK / 256; i++) {
    int idx = b0 + i * 256 + t;
    if (idx < E) {
      int r = row[idx];
      int p = r >> BSH;
      int pos = atomicAdd(&lh[p], 1);
      if (pos < CAP)
        pb[(size_t)p * CAP + pos] =
            make_int2(col[idx] | ((r & 255) << 24), __float_as_int(val[idx]));
    }
  }
}

// ---------------- CSR build, phase B1: per-row counts + bucket sums ----------------
__global__ __launch_bounds__(256) void kB_cnt(const int* __restrict__ ccur,
    const int2* __restrict__ pb, int* __restrict__ cnt, int* __restrict__ bsum,
    int N, int CAP) {
  __shared__ int lc[256];
  __shared__ int ws[4];
  const int b = blockIdx.x;
  const int t = threadIdx.x;
  lc[t] = 0;
  __syncthreads();
  int cb = min(ccur[b], CAP);
  size_t base = (size_t)b * CAP;
  for (int i = t; i < cb; i += 256)
    atomicAdd(&lc[((uint32_t)pb[base + i].x) >> 24], 1);
  __syncthreads();
  int c = lc[t];
  int r = (b << BSH) + t;
  if (r < N) cnt[r] = c;
  int v = c;
  v += __shfl_xor(v, 1); v += __shfl_xor(v, 2); v += __shfl_xor(v, 4);
  v += __shfl_xor(v, 8); v += __shfl_xor(v, 16); v += __shfl_xor(v, 32);
  if ((t & 63) == 0) ws[t >> 6] = v;
  __syncthreads();
  if (t == 0) bsum[b] = ws[0] + ws[1] + ws[2] + ws[3];
}

// ---------------- CSR build: scan of bucket sums (1 block) ----------------
__global__ __launch_bounds__(1024) void k_scanP(const int* __restrict__ bsum,
    int* __restrict__ boff, int* __restrict__ ptrN, int P) {
  __shared__ int ls[1024];
  int t = threadIdx.x;
  int v = (t < P) ? bsum[t] : 0;
  ls[t] = v;
  __syncthreads();
  for (int off = 1; off < 1024; off <<= 1) {
    int u = (t >= off) ? ls[t - off] : 0;
    __syncthreads();
    ls[t] += u;
    __syncthreads();
  }
  if (t < P) boff[t] = ls[t] - v;
  if (t == 1023) *ptrN = ls[1023];
}

// ---------------- CSR build: per-bucket row-offset scan ----------------
__global__ __launch_bounds__(256) void kB_ptr(const int* __restrict__ cnt,
    const int* __restrict__ boff, int* __restrict__ ptr, int N) {
  __shared__ int ls[256];
  int b = blockIdx.x;
  int t = threadIdx.x;
  int r = (b << BSH) + t;
  int v = (r < N) ? cnt[r] : 0;
  ls[t] = v;
  __syncthreads();
  for (int off = 1; off < 256; off <<= 1) {
    int u = (t >= off) ? ls[t - off] : 0;
    __syncthreads();
    ls[t] += u;
    __syncthreads();
  }
  if (r < N) ptr[r] = boff[b] + ls[t] - v;
}

// ---------------- CSR build, phase B2: within-bucket rank scatter ----------------
__global__ __launch_bounds__(256) void kB_scatter(const int* __restrict__ ccur,
    const int2* __restrict__ pb, const int* __restrict__ ptr,
    int2* __restrict__ cv, int CAP) {
  __shared__ int rk[256];
  const int b = blockIdx.x;
  rk[threadIdx.x] = 0;
  __syncthreads();
  int cb = min(ccur[b], CAP);
  size_t base = (size_t)b * CAP;
  for (int i = threadIdx.x; i < cb; i += 256) {
    int2 p2 = pb[base + i];
    int r8 = ((uint32_t)p2.x) >> 24;
    int r = (b << BSH) + r8;
    int rank = atomicAdd(&rk[r8], 1);
    cv[ptr[r] + rank] = make_int2(p2.x & 0x00FFFFFF, p2.y);
  }
}

// ---------------- LayerNorm: bf16 h row -> normalized row ----------------
// FP8OUT=1: emit fp8 e4m3 (spmm gather payload). FP8OUT=0: emit bf16.
template<int FP8OUT>
__global__ __launch_bounds__(256) void k_ln(const ushort* __restrict__ h,
    const float* __restrict__ g, const float* __restrict__ b,
    void* __restrict__ o, int n) {
  int r = (blockIdx.x * 256 + threadIdx.x) >> 6;
  int lane = threadIdx.x & 63;
  if (r >= n) return;
  ushort4 hv = *(const ushort4*)(h + (size_t)r * NHID + lane * 4);
  float v0 = b2f(hv.x), v1 = b2f(hv.y), v2 = b2f(hv.z), v3 = b2f(hv.w);
  float s = v0 + v1 + v2 + v3;
  s += __shfl_xor(s, 1); s += __shfl_xor(s, 2); s += __shfl_xor(s, 4);
  s += __shfl_xor(s, 8); s += __shfl_xor(s, 16); s += __shfl_xor(s, 32);
  float mu = s * (1.f / NHID);
  float d0 = v0 - mu, d1 = v1 - mu, d2 = v2 - mu, d3 = v3 - mu;
  float q = d0 * d0 + d1 * d1 + d2 * d2 + d3 * d3;
  q += __shfl_xor(q, 1); q += __shfl_xor(q, 2); q += __shfl_xor(q, 4);
  q += __shfl_xor(q, 8); q += __shfl_xor(q, 16); q += __shfl_xor(q, 32);
  float rs = rsqrtf(q * (1.f / NHID) + 1e-5f);
  float4 gv = *(const float4*)(g + lane * 4);
  float4 bv = *(const float4*)(b + lane * 4);
  float o0 = d0 * rs * gv.x + bv.x;
  float o1 = d1 * rs * gv.y + bv.y;
  float o2 = d2 * rs * gv.z + bv.z;
  float o3 = d3 * rs * gv.w + bv.w;
  if (FP8OUT) {
    int w = 0;
    w = __builtin_amdgcn_cvt_pk_fp8_f32(o0, o1, w, false);
    w = __builtin_amdgcn_cvt_pk_fp8_f32(o2, o3, w, true);
    ((uint32_t*)o)[(size_t)r * 64 + lane] = (uint32_t)w;
  } else {
    ushort4 t;
    t.x = f2bf(o0); t.y = f2bf(o1); t.z = f2bf(o2); t.w = f2bf(o3);
    *(ushort4*)((ushort*)o + (size_t)r * NHID + lane * 4) = t;
  }
}

// ---------------- SpMM: agg[i] = sum_e val[e] * t8[col[e]]  (fp8 gather) ----------------
// One wave/row; 4 edges/iter (quarter lane>>4), 16B/lane uint4 gathers (16 lanes
// span the 256B fp8 row). Packed v_pk_fma_f32 accumulate; 2-step cross-quarter reduce.
__global__ __launch_bounds__(256) void k_spmm(const int* __restrict__ ptr,
    const int2* __restrict__ cv, const uint32_t* __restrict__ t8,
    ushort* __restrict__ agg, int n) {
  int r = (blockIdx.x * 256 + threadIdx.x) >> 6;
  int lane = threadIdx.x & 63;
  if (r >= n) return;
  int s = ptr[r], e = ptr[r + 1];
  int cnt = e - s;
  int q = lane >> 4;
  int seg = lane & 15;
  f32x2 acc2[8];
#pragma unroll
  for (int j = 0; j < 8; j++) acc2[j] = (f32x2){0.f, 0.f};

  for (int base = 0; base < cnt; base += 64) {
    int idx = s + base + lane;
    int ec = 0; float ev = 0.f;
    if (idx < e) {
      int2 p2 = cv[idx];
      ec = p2.x;
      ev = __uint_as_float((uint32_t)p2.y);
    }
    int lim = min(64, cnt - base);
#pragma unroll 2
    for (int i = 0; i < lim; i += 4) {
      int a = i + q;                    // a <= 63 always
      int c = __shfl(ec, a);
      float v = __shfl(ev, a);          // 0 for out-of-range edges
      f32x2 vv = {v, v};
      uint4 tv = *(const uint4*)(t8 + (size_t)c * 64 + seg * 4);
      f32x2 p;
      p = __builtin_amdgcn_cvt_pk_f32_fp8(tv.x, false);
      acc2[0] = __builtin_elementwise_fma(p, vv, acc2[0]);
      p = __builtin_amdgcn_cvt_pk_f32_fp8(tv.x, true);
      acc2[1] = __builtin_elementwise_fma(p, vv, acc2[1]);
      p = __builtin_amdgcn_cvt_pk_f32_fp8(tv.y, false);
      acc2[2] = __builtin_elementwise_fma(p, vv, acc2[2]);
      p = __builtin_amdgcn_cvt_pk_f32_fp8(tv.y, true);
      acc2[3] = __builtin_elementwise_fma(p, vv, acc2[3]);
      p = __builtin_amdgcn_cvt_pk_f32_fp8(tv.z, false);
      acc2[4] = __builtin_elementwise_fma(p, vv, acc2[4]);
      p = __builtin_amdgcn_cvt_pk_f32_fp8(tv.z, true);
      acc2[5] = __builtin_elementwise_fma(p, vv, acc2[5]);
      p = __builtin_amdgcn_cvt_pk_f32_fp8(tv.w, false);
      acc2[6] = __builtin_elementwise_fma(p, vv, acc2[6]);
      p = __builtin_amdgcn_cvt_pk_f32_fp8(tv.w, true);
      acc2[7] = __builtin_elementwise_fma(p, vv, acc2[7]);
    }
  }

  float accs[16];
#pragma unroll
  for (int j = 0; j < 8; j++) { accs[2 * j] = acc2[j][0]; accs[2 * j + 1] = acc2[j][1]; }
#pragma unroll
  for (int j = 0; j < 16; j++) {
    accs[j] += __shfl_xor(accs[j], 16);
    accs[j] += __shfl_xor(accs[j], 32);
  }
  if (q == 0) {
    short8 o0, o1;
#pragma unroll
    for (int j = 0; j < 8; j++) { o0[j] = (short)f2bf(accs[j]); o1[j] = (short)f2bf(accs[8 + j]); }
    *(short8*)(agg + (size_t)r * NHID + seg * 16) = o0;
    *(short8*)(agg + (size_t)r * NHID + seg * 16 + 8) = o1;
  }
}

// ---------------- input GEMM: H = relu(x @ inW^T + b), fp32 A read + in-reg cvt ----------------
// Full-width 128x256 tile; 4 waves x (32 rows x 256 cols) = acc[2][16].
__global__ __launch_bounds__(256) void k_gemm0(const float* __restrict__ X,
    const ushort* __restrict__ B, const float* __restrict__ bias,
    ushort* __restrict__ H, int M) {
  __shared__ ushort As[128 * 32];
  __shared__ ushort Bs[256 * 32];
  const int t = threadIdx.x;
  const int lane = t & 63;
  const int w = t >> 6;
  const int brow = blockIdx.x * 128;
  const int l15 = lane & 15, hi = lane >> 4;
  const int ar = t >> 1, ah = (t & 1) * 16;   // A staging: row, k-base
  const int agr = min(brow + ar, M - 1);
  const f32x4 z4 = {0.f, 0.f, 0.f, 0.f};
  f32x4 acc[2][16];
#pragma unroll
  for (int m = 0; m < 2; m++)
#pragma unroll
    for (int n = 0; n < 16; n++) acc[m][n] = z4;

  for (int k0 = 0; k0 < KPAD; k0 += 32) {
    __syncthreads();
    // A: fp32 global load + f2bf (identical rounding to cast kernel), 16 vals/thread
    ushort av[16];
#pragma unroll
    for (int c = 0; c < 4; c++) {
      int col = k0 + ah + c * 4;
      float4 v = {0.f, 0.f, 0.f, 0.f};
      if (col + 3 < NFEAT) v = *(const float4*)(X + (size_t)agr * NFEAT + col);
      av[c * 4 + 0] = f2bf(v.x); av[c * 4 + 1] = f2bf(v.y);
      av[c * 4 + 2] = f2bf(v.z); av[c * 4 + 3] = f2bf(v.w);
    }
    // B staging (256x32 bf16 = 16KB) via global_load_lds
#pragma unroll
    for (int c = 0; c < 4; c++) {
      int s = c * 256 + t;
      int rr = s >> 2;
      int kk = (s & 3) * 8;
      const ushort* gb = B + (size_t)rr * KPAD + (k0 + kk);
      __builtin_amdgcn_global_load_lds((const __attribute__((address_space(1))) void*)gb,
          (__attribute__((address_space(3))) void*)(Bs + s * 8), 16, 0, 0);
    }
    *(short8*)(As + ar * 32 + ah) = *(short8*)av;
    *(short8*)(As + ar * 32 + ah + 8) = *(short8*)(av + 8);
    __syncthreads();
    short8 af[2];
#pragma unroll
    for (int m = 0; m < 2; m++)
      af[m] = *(const short8*)(As + (w * 32 + m * 16 + l15) * 32 + hi * 8);
#pragma unroll
    for (int n = 0; n < 16; n++) {
      short8 bf = *(const short8*)(Bs + (n * 16 + l15) * 32 + hi * 8);
      acc[0][n] = __builtin_amdgcn_mfma_f32_16x16x32_bf16(af[0], bf, acc[0][n], 0, 0, 0);
      acc[1][n] = __builtin_amdgcn_mfma_f32_16x16x32_bf16(af[1], bf, acc[1][n], 0, 0, 0);
    }
  }

#pragma unroll
  for (int m = 0; m < 2; m++) {
    int gr0 = brow + w * 32 + m * 16 + hi * 4;
#pragma unroll
    for (int n = 0; n < 16; n++) {
      int gc = n * 16 + l15;
      float bv = bias[gc];
#pragma unroll
      for (int j = 0; j < 4; j++) {
        int gr = gr0 + j;
        if (gr < M)
          H[(size_t)gr * NHID + gc] = f2bf(fmaxf(acc[m][n][j] + bv, 0.f));
      }
    }
  }
}

// ---------------- conv GEMM: full-width 128x256, A read once, bf16 H RMW ----------------
// MODE 1: H += relu(C+bias); MODE 2: H += C+bias
template<int MODE>
__global__ __launch_bounds__(256) void k_gemmc(const ushort* __restrict__ A,
    const ushort* __restrict__ B, const float* __restrict__ bias,
    ushort* __restrict__ H, int M) {
  __shared__ ushort As[128 * 32];
  __shared__ ushort Bs[256 * 32];
  const int t = threadIdx.x;
  const int lane = t & 63;
  const int w = t >> 6;
  const int brow = blockIdx.x * 128;
  const int l15 = lane & 15, hi = lane >> 4;
  const f32x4 z4 = {0.f, 0.f, 0.f, 0.f};
  f32x4 acc[2][16];
#pragma unroll
  for (int m = 0; m < 2; m++)
#pragma unroll
    for (int n = 0; n < 16; n++) acc[m][n] = z4;

  for (int k0 = 0; k0 < NHID; k0 += 32) {
    __syncthreads();
#pragma unroll
    for (int c = 0; c < 2; c++) {
      int s = c * 256 + t;
      int rr = s >> 2;
      int kk = (s & 3) * 8;
      int gr = brow + rr; gr = gr < M ? gr : M - 1;
      const ushort* ga = A + (size_t)gr * NHID + (k0 + kk);
      __builtin_amdgcn_global_load_lds((const __attribute__((address_space(1))) void*)ga,
          (__attribute__((address_space(3))) void*)(As + s * 8), 16, 0, 0);
    }
#pragma unroll
    for (int c = 0; c < 4; c++) {
      int s = c * 256 + t;
      int rr = s >> 2;
      int kk = (s & 3) * 8;
      const ushort* gb = B + (size_t)rr * NHID + (k0 + kk);
      __builtin_amdgcn_global_load_lds((const __attribute__((address_space(1))) void*)gb,
          (__attribute__((address_space(3))) void*)(Bs + s * 8), 16, 0, 0);
    }
    __syncthreads();
    short8 af[2];
#pragma unroll
    for (int m = 0; m < 2; m++)
      af[m] = *(const short8*)(As + (w * 32 + m * 16 + l15) * 32 + hi * 8);
#pragma unroll
    for (int n = 0; n < 16; n++) {
      short8 bf = *(const short8*)(Bs + (n * 16 + l15) * 32 + hi * 8);
      acc[0][n] = __builtin_amdgcn_mfma_f32_16x16x32_bf16(af[0], bf, acc[0][n], 0, 0, 0);
      acc[1][n] = __builtin_amdgcn_mfma_f32_16x16x32_bf16(af[1], bf, acc[1][n], 0, 0, 0);
    }
  }

#pragma unroll
  for (int m = 0; m < 2; m++) {
    int gr0 = brow + w * 32 + m * 16 + hi * 4;
#pragma unroll
    for (int n = 0; n < 16; n++) {
      int gc = n * 16 + l15;
      float bv = bias[gc];
#pragma unroll
      for (int j = 0; j < 4; j++) {
        int gr = gr0 + j;
        if (gr < M) {
          size_t idx = (size_t)gr * NHID + gc;
          float v = acc[m][n][j] + bv;
          if (MODE == 1) H[idx] = f2bf(b2f(H[idx]) + fmaxf(v, 0.f));
          else           H[idx] = f2bf(b2f(H[idx]) + v);
        }
      }
    }
  }
}

// ---------------- output GEMM: z = Anorm @ Wo^T + ob  (skinny N=40, MFMA) ----------------
__global__ __launch_bounds__(256) void k_ogemm(const ushort* __restrict__ A,
    const ushort* __restrict__ Bw, const float* __restrict__ ob,
    float* __restrict__ z, int M) {
  __shared__ ushort As[256 * 32];
  __shared__ ushort Bs[NCPAD * 264];
  const int t = threadIdx.x;
  const int lane = t & 63;
  const int wid = t >> 6;
  const int brow = blockIdx.x * 256;
  const int wr = wid * 64;
  const int l15 = lane & 15, hi = lane >> 4;
  const f32x4 z4 = {0.f, 0.f, 0.f, 0.f};
  f32x4 acc[4][3];
#pragma unroll
  for (int m = 0; m < 4; m++)
#pragma unroll
    for (int n = 0; n < 3; n++) acc[m][n] = z4;

  for (int i = t; i < NCPAD * 33; i += 256) {
    int r = i / 33, cc = i % 33;
    if (cc < 32)
      *(short8*)(Bs + r * 264 + cc * 8) = *(const short8*)(Bw + r * 256 + cc * 8);
  }

  for (int k0 = 0; k0 < 256; k0 += 32) {
    __syncthreads();
#pragma unroll
    for (int c = 0; c < 4; c++) {
      int s = c * 256 + t;
      int r = s >> 2;
      int kk = (s & 3) * 8;
      int gr = brow + r; gr = gr < M ? gr : M - 1;
      const ushort* ga = A + (size_t)gr * NHID + (k0 + kk);
      __builtin_amdgcn_global_load_lds((const __attribute__((address_space(1))) void*)ga,
          (__attribute__((address_space(3))) void*)(As + s * 8), 16, 0, 0);
    }
    __syncthreads();
    short8 af[4], bf[3];
#pragma unroll
    for (int m = 0; m < 4; m++)
      af[m] = *(const short8*)(As + (wr + m * 16 + l15) * 32 + hi * 8);
#pragma unroll
    for (int n = 0; n < 3; n++)
      bf[n] = *(const short8*)(Bs + (n * 16 + l15) * 264 + k0 + hi * 8);
#pragma unroll
    for (int m = 0; m < 4; m++)
#pragma unroll
      for (int n = 0; n < 3; n++)
        acc[m][n] = __builtin_amdgcn_mfma_f32_16x16x32_bf16(af[m], bf[n], acc[m][n], 0, 0, 0);
  }

#pragma unroll
  for (int m = 0; m < 4; m++) {
    int gr0 = brow + wr + m * 16 + hi * 4;
#pragma unroll
    for (int n = 0; n < 3; n++) {
      int gc = n * 16 + l15;
      if (gc < NCLS) {
        float bv = ob[gc];
#pragma unroll
        for (int j = 0; j < 4; j++) {
          int gr = gr0 + j;
          if (gr < M) z[(size_t)gr * NCLS + gc] = acc[m][n][j] + bv;
        }
      }
    }
  }
}

extern "C" void kernel_launch(void* const* d_in, const int* in_sizes, int n_in,
                              void* d_out, int out_size, void* d_ws, size_t ws_size,
                              hipStream_t stream) {
  const float* x     = (const float*)d_in[0];
  const int*   row   = (const int*)d_in[1];
  const int*   col   = (const int*)d_in[2];
  const float* val   = (const float*)d_in[3];
  const float* inW   = (const float*)d_in[4];
  const float* inB   = (const float*)d_in[5];
  const float* convW = (const float*)d_in[6];
  const float* convB = (const float*)d_in[7];
  const float* lnG   = (const float*)d_in[8];
  const float* lnB   = (const float*)d_in[9];
  const float* outG  = (const float*)d_in[10];
  const float* outB  = (const float*)d_in[11];
  const float* outW  = (const float*)d_in[12];
  const float* outb  = (const float*)d_in[13];
  const int N = in_sizes[0] / NFEAT;
  const int E = in_sizes[1];
  float* z = (float*)d_out;

  const int P   = (N + 255) >> BSH;
  const int CAP = ((((E + P - 1) / P) * 5 / 4 + 256) + 15) & ~15;

  char* wsp = (char*)d_ws;
  size_t off = 0;
  auto alloc = [&](size_t bytes) {
    void* p = wsp + off;
    off += (bytes + 255) & ~(size_t)255;
    return p;
  };
  ushort*   h   = (ushort*)alloc((size_t)N * NHID * 2);   // bf16 residual stream
  ushort*   tb  = (ushort*)alloc((size_t)N * NHID * 2);
  ushort*   ab  = (ushort*)alloc((size_t)N * NHID * 2);
  uint32_t* t8  = (uint32_t*)alloc((size_t)N * 64 * 4);   // fp8 LN output (256B/row)
  ushort*   wbi = (ushort*)alloc((size_t)NHID * KPAD * 2);
  ushort*   wbc = (ushort*)alloc((size_t)NLAY * NHID * NHID * 2);
  ushort*   wbo = (ushort*)alloc((size_t)NCPAD * NHID * 2);
  int*   cnt  = (int*)alloc((size_t)N * 4);
  int*   ptr  = (int*)alloc((size_t)(N + 1) * 4);
  int*   ccur = (int*)alloc((size_t)P * 4);
  int*   bsum = (int*)alloc((size_t)P * 4);
  int*   boff = (int*)alloc((size_t)P * 4);
  int2*  cv   = (int2*)alloc((size_t)E * 8);
  int2*  pb   = (int2*)alloc((size_t)P * CAP * 8);

  // weight casts (inW padded to 512, convW straight, outW zero-padded to 48 rows)
  {
    int tot = NHID * (KPAD >> 2);
    k_cast_pad<<<(tot + 255) / 256, 256, 0, stream>>>(inW, wbi, NHID, NFEAT, KPAD);
    tot = NLAY * NHID * (NHID >> 2);
    k_cast_pad<<<(tot + 255) / 256, 256, 0, stream>>>(convW, wbc, NLAY * NHID, NHID, NHID);
    hipMemsetAsync(wbo, 0, (size_t)NCPAD * NHID * 2, stream);
    tot = NCLS * (NHID >> 2);
    k_cast_pad<<<(tot + 255) / 256, 256, 0, stream>>>(outW, wbo, NCLS, NHID, NHID);
  }

  const int ng = (N + 127) / 128;

  // input layer: h = relu(x @ inW^T + inB), fp32 x read directly
  k_gemm0<<<ng, 256, 0, stream>>>(x, wbi, inB, h, N);

  // CSR build: locality-binned two-phase counting sort, hierarchical scan
  hipMemsetAsync(ccur, 0, (size_t)P * 4, stream);
  kA_scatter<<<(E + CHUNK - 1) / CHUNK, 256, 0, stream>>>(row, col, val, ccur, pb, E, P, CAP);
  kB_cnt<<<P, 256, 0, stream>>>(ccur, pb, cnt, bsum, N, CAP);
  k_scanP<<<1, 1024, 0, stream>>>(bsum, boff, ptr + N, P);
  kB_ptr<<<P, 256, 0, stream>>>(cnt, boff, ptr, N);
  kB_scatter<<<P, 256, 0, stream>>>(ccur, pb, ptr, cv, CAP);

  int nwb = (N + 3) / 4;
  for (int i = 0; i < NLAY; i++) {
    k_ln<1><<<nwb, 256, 0, stream>>>(h, lnG + i * NHID, lnB + i * NHID, t8, N);
    k_spmm<<<nwb, 256, 0, stream>>>(ptr, cv, t8, ab, N);
    if (i < NLAY - 1)
      k_gemmc<1><<<ng, 256, 0, stream>>>(ab, wbc + (size_t)i * NHID * NHID,
                                         convB + i * NHID, h, N);
    else
      k_gemmc<2><<<ng, 256, 0, stream>>>(ab, wbc + (size_t)i * NHID * NHID,
                                         convB + i * NHID, h, N);
  }

  k_ln<0><<<nwb, 256, 0, stream>>>(h, outG, outB, tb, N);
  k_ogemm<<<(N + 255) / 256, 256, 0, stream>>>(tb, wbo, outb, z, N);
}

// Round 10
// 1263.551 us; speedup vs baseline: 1.2939x; 1.2939x over previous
//
#include <hip/hip_runtime.h>
#include <stdint.h>

#define NFEAT 500
#define KPAD  512
#define NHID  256
#define NCLS  40
#define NCPAD 48
#define NLAY  5
#define BSH   8      // coarse bucket = row >> 8
#define CHUNK 8192   // edges per kA block

typedef __attribute__((ext_vector_type(8))) short short8;
typedef __attribute__((ext_vector_type(4))) float f32x4;
typedef __attribute__((ext_vector_type(2))) float f32x2;

__device__ __forceinline__ ushort f2bf(float f) {
  uint32_t u = __float_as_uint(f);
  u += 0x7fffu + ((u >> 16) & 1u);
  return (ushort)(u >> 16);
}
__device__ __forceinline__ float b2f(ushort h) {
  return __uint_as_float(((uint32_t)h) << 16);
}

// ---------------- casts (fp32 -> bf16, with K padding) ----------------
__global__ __launch_bounds__(256) void k_cast_pad(const float* __restrict__ src,
    ushort* __restrict__ dst, int rows, int scol, int dcol) {
  int id = blockIdx.x * 256 + threadIdx.x;
  int cpr = dcol >> 2;
  if (id >= rows * cpr) return;
  int r = id / cpr;
  int c = (id % cpr) * 4;
  float4 v;
  if (c + 3 < scol) {
    v = *(const float4*)(src + (size_t)r * scol + c);
  } else {
    v.x = (c + 0 < scol) ? src[(size_t)r * scol + c + 0] : 0.f;
    v.y = (c + 1 < scol) ? src[(size_t)r * scol + c + 1] : 0.f;
    v.z = (c + 2 < scol) ? src[(size_t)r * scol + c + 2] : 0.f;
    v.w = (c + 3 < scol) ? src[(size_t)r * scol + c + 3] : 0.f;
  }
  ushort4 o;
  o.x = f2bf(v.x); o.y = f2bf(v.y); o.z = f2bf(v.z); o.w = f2bf(v.w);
  *(ushort4*)(dst + (size_t)r * dcol + c) = o;
}

// ---------------- CSR build, phase A: coarse bucket scatter ----------------
__global__ __launch_bounds__(256) void kA_scatter(const int* __restrict__ row,
    const int* __restrict__ col, const float* __restrict__ val,
    int* __restrict__ ccur, int2* __restrict__ pb, int E, int P, int CAP) {
  __shared__ int lh[512];
  const int t = threadIdx.x;
  const int b0 = blockIdx.x * CHUNK;
  for (int i = t; i < P; i += 256) lh[i] = 0;
  __syncthreads();
#pragma unroll 4
  for (int i = 0; i < CHUNK / 256; i++) {
    int idx = b0 + i * 256 + t;
    if (idx < E) atomicAdd(&lh[row[idx] >> BSH], 1);
  }
  __syncthreads();
  for (int i = t; i < P; i += 256) {
    int c = lh[i];
    lh[i] = (c > 0) ? atomicAdd(&ccur[i], c) : 0;
  }
  __syncthreads();
#pragma unroll 4
  for (int i = 0; i < CHUNK / 256; i++) {
    int idx = b0 + i * 256 + t;
    if (idx < E) {
      int r = row[idx];
      int p = r >> BSH;
      int pos = atomicAdd(&lh[p], 1);
      if (pos < CAP)
        pb[(size_t)p * CAP + pos] =
            make_int2(col[idx] | ((r & 255) << 24), __float_as_int(val[idx]));
    }
  }
}

// ---------------- CSR build, phase B1: per-row counts + bucket sums ----------------
__global__ __launch_bounds__(256) void kB_cnt(const int* __restrict__ ccur,
    const int2* __restrict__ pb, int* __restrict__ cnt, int* __restrict__ bsum,
    int N, int CAP) {
  __shared__ int lc[256];
  __shared__ int ws[4];
  const int b = blockIdx.x;
  const int t = threadIdx.x;
  lc[t] = 0;
  __syncthreads();
  int cb = min(ccur[b], CAP);
  size_t base = (size_t)b * CAP;
  for (int i = t; i < cb; i += 256)
    atomicAdd(&lc[((uint32_t)pb[base + i].x) >> 24], 1);
  __syncthreads();
  int c = lc[t];
  int r = (b << BSH) + t;
  if (r < N) cnt[r] = c;
  int v = c;
  v += __shfl_xor(v, 1); v += __shfl_xor(v, 2); v += __shfl_xor(v, 4);
  v += __shfl_xor(v, 8); v += __shfl_xor(v, 16); v += __shfl_xor(v, 32);
  if ((t & 63) == 0) ws[t >> 6] = v;
  __syncthreads();
  if (t == 0) bsum[b] = ws[0] + ws[1] + ws[2] + ws[3];
}

// ---------------- CSR build: scan of bucket sums (1 block) ----------------
__global__ __launch_bounds__(1024) void k_scanP(const int* __restrict__ bsum,
    int* __restrict__ boff, int* __restrict__ ptrN, int P) {
  __shared__ int ls[1024];
  int t = threadIdx.x;
  int v = (t < P) ? bsum[t] : 0;
  ls[t] = v;
  __syncthreads();
  for (int off = 1; off < 1024; off <<= 1) {
    int u = (t >= off) ? ls[t - off] : 0;
    __syncthreads();
    ls[t] += u;
    __syncthreads();
  }
  if (t < P) boff[t] = ls[t] - v;
  if (t == 1023) *ptrN = ls[1023];
}

// ---------------- CSR build: per-bucket row-offset scan ----------------
__global__ __launch_bounds__(256) void kB_ptr(const int* __restrict__ cnt,
    const int* __restrict__ boff, int* __restrict__ ptr, int N) {
  __shared__ int ls[256];
  int b = blockIdx.x;
  int t = threadIdx.x;
  int r = (b << BSH) + t;
  int v = (r < N) ? cnt[r] : 0;
  ls[t] = v;
  __syncthreads();
  for (int off = 1; off < 256; off <<= 1) {
    int u = (t >= off) ? ls[t - off] : 0;
    __syncthreads();
    ls[t] += u;
    __syncthreads();
  }
  if (r < N) ptr[r] = boff[b] + ls[t] - v;
}

// ---------------- CSR build, phase B2: within-bucket rank scatter ----------------
__global__ __launch_bounds__(256) void kB_scatter(const int* __restrict__ ccur,
    const int2* __restrict__ pb, const int* __restrict__ ptr,
    int2* __restrict__ cv, int CAP) {
  __shared__ int rk[256];
  const int b = blockIdx.x;
  rk[threadIdx.x] = 0;
  __syncthreads();
  int cb = min(ccur[b], CAP);
  size_t base = (size_t)b * CAP;
  for (int i = threadIdx.x; i < cb; i += 256) {
    int2 p2 = pb[base + i];
    int r8 = ((uint32_t)p2.x) >> 24;
    int r = (b << BSH) + r8;
    int rank = atomicAdd(&rk[r8], 1);
    cv[ptr[r] + rank] = make_int2(p2.x & 0x00FFFFFF, p2.y);
  }
}

// ---------------- LayerNorm: bf16 h row -> normalized row ----------------
// FP8OUT=1: emit fp8 e4m3 (spmm gather payload). FP8OUT=0: emit bf16.
template<int FP8OUT>
__global__ __launch_bounds__(256) void k_ln(const ushort* __restrict__ h,
    const float* __restrict__ g, const float* __restrict__ b,
    void* __restrict__ o, int n) {
  int r = (blockIdx.x * 256 + threadIdx.x) >> 6;
  int lane = threadIdx.x & 63;
  if (r >= n) return;
  ushort4 hv = *(const ushort4*)(h + (size_t)r * NHID + lane * 4);
  float v0 = b2f(hv.x), v1 = b2f(hv.y), v2 = b2f(hv.z), v3 = b2f(hv.w);
  float s = v0 + v1 + v2 + v3;
  s += __shfl_xor(s, 1); s += __shfl_xor(s, 2); s += __shfl_xor(s, 4);
  s += __shfl_xor(s, 8); s += __shfl_xor(s, 16); s += __shfl_xor(s, 32);
  float mu = s * (1.f / NHID);
  float d0 = v0 - mu, d1 = v1 - mu, d2 = v2 - mu, d3 = v3 - mu;
  float q = d0 * d0 + d1 * d1 + d2 * d2 + d3 * d3;
  q += __shfl_xor(q, 1); q += __shfl_xor(q, 2); q += __shfl_xor(q, 4);
  q += __shfl_xor(q, 8); q += __shfl_xor(q, 16); q += __shfl_xor(q, 32);
  float rs = rsqrtf(q * (1.f / NHID) + 1e-5f);
  float4 gv = *(const float4*)(g + lane * 4);
  float4 bv = *(const float4*)(b + lane * 4);
  float o0 = d0 * rs * gv.x + bv.x;
  float o1 = d1 * rs * gv.y + bv.y;
  float o2 = d2 * rs * gv.z + bv.z;
  float o3 = d3 * rs * gv.w + bv.w;
  if (FP8OUT) {
    int w = 0;
    w = __builtin_amdgcn_cvt_pk_fp8_f32(o0, o1, w, false);
    w = __builtin_amdgcn_cvt_pk_fp8_f32(o2, o3, w, true);
    ((uint32_t*)o)[(size_t)r * 64 + lane] = (uint32_t)w;
  } else {
    ushort4 t;
    t.x = f2bf(o0); t.y = f2bf(o1); t.z = f2bf(o2); t.w = f2bf(o3);
    *(ushort4*)((ushort*)o + (size_t)r * NHID + lane * 4) = t;
  }
}

// ---------------- SpMM: agg[i] = sum_e val[e] * t8[col[e]]  (fp8 gather) ----------------
// One wave/row; 4 edges/iter (quarter lane>>4), 16B/lane uint4 gathers (16 lanes
// span the 256B fp8 row). Packed v_pk_fma_f32 accumulate; 2-step cross-quarter reduce.
__global__ __launch_bounds__(256) void k_spmm(const int* __restrict__ ptr,
    const int2* __restrict__ cv, const uint32_t* __restrict__ t8,
    ushort* __restrict__ agg, int n) {
  int r = (blockIdx.x * 256 + threadIdx.x) >> 6;
  int lane = threadIdx.x & 63;
  if (r >= n) return;
  int s = ptr[r], e = ptr[r + 1];
  int cnt = e - s;
  int q = lane >> 4;
  int seg = lane & 15;
  f32x2 acc2[8];
#pragma unroll
  for (int j = 0; j < 8; j++) acc2[j] = (f32x2){0.f, 0.f};

  for (int base = 0; base < cnt; base += 64) {
    int idx = s + base + lane;
    int ec = 0; float ev = 0.f;
    if (idx < e) {
      int2 p2 = cv[idx];
      ec = p2.x;
      ev = __uint_as_float((uint32_t)p2.y);
    }
    int lim = min(64, cnt - base);
#pragma unroll 2
    for (int i = 0; i < lim; i += 4) {
      int a = i + q;                    // a <= 63 always
      int c = __shfl(ec, a);
      float v = __shfl(ev, a);          // 0 for out-of-range edges
      f32x2 vv = {v, v};
      uint4 tv = *(const uint4*)(t8 + (size_t)c * 64 + seg * 4);
      f32x2 p;
      p = __builtin_amdgcn_cvt_pk_f32_fp8(tv.x, false);
      acc2[0] = __builtin_elementwise_fma(p, vv, acc2[0]);
      p = __builtin_amdgcn_cvt_pk_f32_fp8(tv.x, true);
      acc2[1] = __builtin_elementwise_fma(p, vv, acc2[1]);
      p = __builtin_amdgcn_cvt_pk_f32_fp8(tv.y, false);
      acc2[2] = __builtin_elementwise_fma(p, vv, acc2[2]);
      p = __builtin_amdgcn_cvt_pk_f32_fp8(tv.y, true);
      acc2[3] = __builtin_elementwise_fma(p, vv, acc2[3]);
      p = __builtin_amdgcn_cvt_pk_f32_fp8(tv.z, false);
      acc2[4] = __builtin_elementwise_fma(p, vv, acc2[4]);
      p = __builtin_amdgcn_cvt_pk_f32_fp8(tv.z, true);
      acc2[5] = __builtin_elementwise_fma(p, vv, acc2[5]);
      p = __builtin_amdgcn_cvt_pk_f32_fp8(tv.w, false);
      acc2[6] = __builtin_elementwise_fma(p, vv, acc2[6]);
      p = __builtin_amdgcn_cvt_pk_f32_fp8(tv.w, true);
      acc2[7] = __builtin_elementwise_fma(p, vv, acc2[7]);
    }
  }

  float accs[16];
#pragma unroll
  for (int j = 0; j < 8; j++) { accs[2 * j] = acc2[j][0]; accs[2 * j + 1] = acc2[j][1]; }
#pragma unroll
  for (int j = 0; j < 16; j++) {
    accs[j] += __shfl_xor(accs[j], 16);
    accs[j] += __shfl_xor(accs[j], 32);
  }
  if (q == 0) {
    short8 o0, o1;
#pragma unroll
    for (int j = 0; j < 8; j++) { o0[j] = (short)f2bf(accs[j]); o1[j] = (short)f2bf(accs[8 + j]); }
    *(short8*)(agg + (size_t)r * NHID + seg * 16) = o0;
    *(short8*)(agg + (size_t)r * NHID + seg * 16 + 8) = o1;
  }
}

// ---------------- MFMA GEMM: C = A(MxK,bf16) @ B(NxK,bf16)^T, fused epilogue ----------------
// H is bf16. MODE 0: H = relu(C+bias); 1: H += relu(C+bias); 2: H += C+bias
template<int MODE>
__global__ __launch_bounds__(256) void k_gemm(const ushort* __restrict__ A,
    const ushort* __restrict__ B, const float* __restrict__ bias,
    ushort* __restrict__ H, int M, int K) {
  __shared__ ushort As[128 * 32];
  __shared__ ushort Bs[128 * 32];
  const int t = threadIdx.x;
  const int lane = t & 63;
  const int wid = t >> 6;
  const int brow = blockIdx.x * 128;
  const int bcol = blockIdx.y * 128;
  const int wr = (wid >> 1) * 64;
  const int wc = (wid & 1) * 64;
  const int l15 = lane & 15, hi = lane >> 4;
  const f32x4 z4 = {0.f, 0.f, 0.f, 0.f};
  f32x4 acc[4][4];
  for (int m = 0; m < 4; m++)
    for (int n = 0; n < 4; n++) acc[m][n] = z4;

  for (int k0 = 0; k0 < K; k0 += 32) {
    __syncthreads();
#pragma unroll
    for (int c = 0; c < 2; c++) {
      int s = c * 256 + t;
      int r = s >> 2;
      int kk = (s & 3) * 8;
      int gr = brow + r; gr = gr < M ? gr : M - 1;
      const ushort* ga = A + (size_t)gr * K + (k0 + kk);
      __builtin_amdgcn_global_load_lds((const __attribute__((address_space(1))) void*)ga,
          (__attribute__((address_space(3))) void*)(As + s * 8), 16, 0, 0);
      const ushort* gb = B + (size_t)(bcol + r) * K + (k0 + kk);
      __builtin_amdgcn_global_load_lds((const __attribute__((address_space(1))) void*)gb,
          (__attribute__((address_space(3))) void*)(Bs + s * 8), 16, 0, 0);
    }
    __syncthreads();
    short8 af[4], bf[4];
#pragma unroll
    for (int m = 0; m < 4; m++)
      af[m] = *(const short8*)(As + (wr + m * 16 + l15) * 32 + hi * 8);
#pragma unroll
    for (int n = 0; n < 4; n++)
      bf[n] = *(const short8*)(Bs + (wc + n * 16 + l15) * 32 + hi * 8);
#pragma unroll
    for (int m = 0; m < 4; m++)
#pragma unroll
      for (int n = 0; n < 4; n++)
        acc[m][n] = __builtin_amdgcn_mfma_f32_16x16x32_bf16(af[m], bf[n], acc[m][n], 0, 0, 0);
  }

#pragma unroll
  for (int m = 0; m < 4; m++) {
    int gr0 = brow + wr + m * 16 + hi * 4;
#pragma unroll
    for (int n = 0; n < 4; n++) {
      int gc = bcol + wc + n * 16 + l15;
      float bv = bias[gc];
#pragma unroll
      for (int j = 0; j < 4; j++) {
        int gr = gr0 + j;
        if (gr < M) {
          size_t idx = (size_t)gr * NHID + gc;
          float v = acc[m][n][j] + bv;
          if (MODE == 0)      H[idx] = f2bf(fmaxf(v, 0.f));
          else if (MODE == 1) H[idx] = f2bf(b2f(H[idx]) + fmaxf(v, 0.f));
          else                H[idx] = f2bf(b2f(H[idx]) + v);
        }
      }
    }
  }
}

// ---------------- output GEMM: z = Anorm @ Wo^T + ob  (skinny N=40, MFMA) ----------------
__global__ __launch_bounds__(256) void k_ogemm(const ushort* __restrict__ A,
    const ushort* __restrict__ Bw, const float* __restrict__ ob,
    float* __restrict__ z, int M) {
  __shared__ ushort As[256 * 32];
  __shared__ ushort Bs[NCPAD * 264];
  const int t = threadIdx.x;
  const int lane = t & 63;
  const int wid = t >> 6;
  const int brow = blockIdx.x * 256;
  const int wr = wid * 64;
  const int l15 = lane & 15, hi = lane >> 4;
  const f32x4 z4 = {0.f, 0.f, 0.f, 0.f};
  f32x4 acc[4][3];
#pragma unroll
  for (int m = 0; m < 4; m++)
#pragma unroll
    for (int n = 0; n < 3; n++) acc[m][n] = z4;

  for (int i = t; i < NCPAD * 33; i += 256) {
    int r = i / 33, cc = i % 33;
    if (cc < 32)
      *(short8*)(Bs + r * 264 + cc * 8) = *(const short8*)(Bw + r * 256 + cc * 8);
  }

  for (int k0 = 0; k0 < 256; k0 += 32) {
    __syncthreads();
#pragma unroll
    for (int c = 0; c < 4; c++) {
      int s = c * 256 + t;
      int r = s >> 2;
      int kk = (s & 3) * 8;
      int gr = brow + r; gr = gr < M ? gr : M - 1;
      const ushort* ga = A + (size_t)gr * NHID + (k0 + kk);
      __builtin_amdgcn_global_load_lds((const __attribute__((address_space(1))) void*)ga,
          (__attribute__((address_space(3))) void*)(As + s * 8), 16, 0, 0);
    }
    __syncthreads();
    short8 af[4], bf[3];
#pragma unroll
    for (int m = 0; m < 4; m++)
      af[m] = *(const short8*)(As + (wr + m * 16 + l15) * 32 + hi * 8);
#pragma unroll
    for (int n = 0; n < 3; n++)
      bf[n] = *(const short8*)(Bs + (n * 16 + l15) * 264 + k0 + hi * 8);
#pragma unroll
    for (int m = 0; m < 4; m++)
#pragma unroll
      for (int n = 0; n < 3; n++)
        acc[m][n] = __builtin_amdgcn_mfma_f32_16x16x32_bf16(af[m], bf[n], acc[m][n], 0, 0, 0);
  }

#pragma unroll
  for (int m = 0; m < 4; m++) {
    int gr0 = brow + wr + m * 16 + hi * 4;
#pragma unroll
    for (int n = 0; n < 3; n++) {
      int gc = n * 16 + l15;
      if (gc < NCLS) {
        float bv = ob[gc];
#pragma unroll
        for (int j = 0; j < 4; j++) {
          int gr = gr0 + j;
          if (gr < M) z[(size_t)gr * NCLS + gc] = acc[m][n][j] + bv;
        }
      }
    }
  }
}

extern "C" void kernel_launch(void* const* d_in, const int* in_sizes, int n_in,
                              void* d_out, int out_size, void* d_ws, size_t ws_size,
                              hipStream_t stream) {
  const float* x     = (const float*)d_in[0];
  const int*   row   = (const int*)d_in[1];
  const int*   col   = (const int*)d_in[2];
  const float* val   = (const float*)d_in[3];
  const float* inW   = (const float*)d_in[4];
  const float* inB   = (const float*)d_in[5];
  const float* convW = (const float*)d_in[6];
  const float* convB = (const float*)d_in[7];
  const float* lnG   = (const float*)d_in[8];
  const float* lnB   = (const float*)d_in[9];
  const float* outG  = (const float*)d_in[10];
  const float* outB  = (const float*)d_in[11];
  const float* outW  = (const float*)d_in[12];
  const float* outb  = (const float*)d_in[13];
  const int N = in_sizes[0] / NFEAT;
  const int E = in_sizes[1];
  float* z = (float*)d_out;

  const int P   = (N + 255) >> BSH;
  const int CAP = ((((E + P - 1) / P) * 5 / 4 + 256) + 15) & ~15;

  char* wsp = (char*)d_ws;
  size_t off = 0;
  auto alloc = [&](size_t bytes) {
    void* p = wsp + off;
    off += (bytes + 255) & ~(size_t)255;
    return p;
  };
  ushort*   h   = (ushort*)alloc((size_t)N * NHID * 2);   // bf16 residual stream
  ushort*   tb  = (ushort*)alloc((size_t)N * NHID * 2);
  ushort*   ab  = (ushort*)alloc((size_t)N * NHID * 2);
  uint32_t* t8  = (uint32_t*)alloc((size_t)N * 64 * 4);   // fp8 LN output (256B/row)
  ushort*   xb  = (ushort*)alloc((size_t)N * KPAD * 2);   // also CSR scratch after input gemm
  ushort*   wbi = (ushort*)alloc((size_t)NHID * KPAD * 2);
  ushort*   wbc = (ushort*)alloc((size_t)NLAY * NHID * NHID * 2);
  ushort*   wbo = (ushort*)alloc((size_t)NCPAD * NHID * 2);
  int*   cnt  = (int*)alloc((size_t)N * 4);
  int*   ptr  = (int*)alloc((size_t)(N + 1) * 4);
  int*   ccur = (int*)alloc((size_t)P * 4);
  int*   bsum = (int*)alloc((size_t)P * 4);
  int*   boff = (int*)alloc((size_t)P * 4);
  int2*  cv   = (int2*)alloc((size_t)E * 8);
  int2*  pb   = (int2*)xb;   // aliases xb (dead after input gemm)

  // bf16 casts
  {
    int tot = N * (KPAD >> 2);
    k_cast_pad<<<(tot + 255) / 256, 256, 0, stream>>>(x, xb, N, NFEAT, KPAD);
    tot = NHID * (KPAD >> 2);
    k_cast_pad<<<(tot + 255) / 256, 256, 0, stream>>>(inW, wbi, NHID, NFEAT, KPAD);
    tot = NLAY * NHID * (NHID >> 2);
    k_cast_pad<<<(tot + 255) / 256, 256, 0, stream>>>(convW, wbc, NLAY * NHID, NHID, NHID);
    hipMemsetAsync(wbo, 0, (size_t)NCPAD * NHID * 2, stream);
    tot = NCLS * (NHID >> 2);
    k_cast_pad<<<(tot + 255) / 256, 256, 0, stream>>>(outW, wbo, NCLS, NHID, NHID);
  }

  // input layer first (so xb can be reused as CSR scratch)
  dim3 gg((N + 127) / 128, NHID / 128);
  k_gemm<0><<<gg, 256, 0, stream>>>(xb, wbi, inB, h, N, KPAD);

  // CSR build: locality-binned two-phase counting sort, hierarchical scan
  hipMemsetAsync(ccur, 0, (size_t)P * 4, stream);
  kA_scatter<<<(E + CHUNK - 1) / CHUNK, 256, 0, stream>>>(row, col, val, ccur, pb, E, P, CAP);
  kB_cnt<<<P, 256, 0, stream>>>(ccur, pb, cnt, bsum, N, CAP);
  k_scanP<<<1, 1024, 0, stream>>>(bsum, boff, ptr + N, P);
  kB_ptr<<<P, 256, 0, stream>>>(cnt, boff, ptr, N);
  kB_scatter<<<P, 256, 0, stream>>>(ccur, pb, ptr, cv, CAP);

  int nwb = (N + 3) / 4;
  for (int i = 0; i < NLAY; i++) {
    k_ln<1><<<nwb, 256, 0, stream>>>(h, lnG + i * NHID, lnB + i * NHID, t8, N);
    k_spmm<<<nwb, 256, 0, stream>>>(ptr, cv, t8, ab, N);
    if (i < NLAY - 1)
      k_gemm<1><<<gg, 256, 0, stream>>>(ab, wbc + (size_t)i * NHID * NHID,
                                        convB + i * NHID, h, N, NHID);
    else
      k_gemm<2><<<gg, 256, 0, stream>>>(ab, wbc + (size_t)i * NHID * NHID,
                                        convB + i * NHID, h, N, NHID);
  }

  k_ln<0><<<nwb, 256, 0, stream>>>(h, outG, outB, tb, N);
  k_ogemm<<<(N + 255) / 256, 256, 0, stream>>>(tb, wbo, outb, z, N);
}

// Round 11
// 1258.876 us; speedup vs baseline: 1.2987x; 1.0037x over previous
//
#include <hip/hip_runtime.h>
#include <stdint.h>

#define NFEAT 500
#define KPAD  512
#define NHID  256
#define NCLS  40
#define NCPAD 48
#define NLAY  5
#define BSH   8      // coarse bucket = row >> 8
#define CHUNK 8192   // edges per kA block

typedef __attribute__((ext_vector_type(8))) short short8;
typedef __attribute__((ext_vector_type(4))) float f32x4;
typedef __attribute__((ext_vector_type(2))) float f32x2;

__device__ __forceinline__ ushort f2bf(float f) {
  uint32_t u = __float_as_uint(f);
  u += 0x7fffu + ((u >> 16) & 1u);
  return (ushort)(u >> 16);
}
__device__ __forceinline__ float b2f(ushort h) {
  return __uint_as_float(((uint32_t)h) << 16);
}

// ---------------- casts (fp32 -> bf16, with K padding) ----------------
__global__ __launch_bounds__(256) void k_cast_pad(const float* __restrict__ src,
    ushort* __restrict__ dst, int rows, int scol, int dcol) {
  int id = blockIdx.x * 256 + threadIdx.x;
  int cpr = dcol >> 2;
  if (id >= rows * cpr) return;
  int r = id / cpr;
  int c = (id % cpr) * 4;
  float4 v;
  if (c + 3 < scol) {
    v = *(const float4*)(src + (size_t)r * scol + c);
  } else {
    v.x = (c + 0 < scol) ? src[(size_t)r * scol + c + 0] : 0.f;
    v.y = (c + 1 < scol) ? src[(size_t)r * scol + c + 1] : 0.f;
    v.z = (c + 2 < scol) ? src[(size_t)r * scol + c + 2] : 0.f;
    v.w = (c + 3 < scol) ? src[(size_t)r * scol + c + 3] : 0.f;
  }
  ushort4 o;
  o.x = f2bf(v.x); o.y = f2bf(v.y); o.z = f2bf(v.z); o.w = f2bf(v.w);
  *(ushort4*)(dst + (size_t)r * dcol + c) = o;
}

// ---------------- CSR build, phase A: coarse bucket scatter ----------------
__global__ __launch_bounds__(256) void kA_scatter(const int* __restrict__ row,
    const int* __restrict__ col, const float* __restrict__ val,
    int* __restrict__ ccur, int2* __restrict__ pb, int E, int P, int CAP) {
  __shared__ int lh[512];
  const int t = threadIdx.x;
  const int b0 = blockIdx.x * CHUNK;
  for (int i = t; i < P; i += 256) lh[i] = 0;
  __syncthreads();
#pragma unroll 4
  for (int i = 0; i < CHUNK / 256; i++) {
    int idx = b0 + i * 256 + t;
    if (idx < E) atomicAdd(&lh[row[idx] >> BSH], 1);
  }
  __syncthreads();
  for (int i = t; i < P; i += 256) {
    int c = lh[i];
    lh[i] = (c > 0) ? atomicAdd(&ccur[i], c) : 0;
  }
  __syncthreads();
#pragma unroll 4
  for (int i = 0; i < CHUNK / 256; i++) {
    int idx = b0 + i * 256 + t;
    if (idx < E) {
      int r = row[idx];
      int p = r >> BSH;
      int pos = atomicAdd(&lh[p], 1);
      if (pos < CAP)
        pb[(size_t)p * CAP + pos] =
            make_int2(col[idx] | ((r & 255) << 24), __float_as_int(val[idx]));
    }
  }
}

// ---------------- CSR build, phase B1: per-row counts + bucket sums ----------------
__global__ __launch_bounds__(256) void kB_cnt(const int* __restrict__ ccur,
    const int2* __restrict__ pb, int* __restrict__ cnt, int* __restrict__ bsum,
    int N, int CAP) {
  __shared__ int lc[256];
  __shared__ int ws[4];
  const int b = blockIdx.x;
  const int t = threadIdx.x;
  lc[t] = 0;
  __syncthreads();
  int cb = min(ccur[b], CAP);
  size_t base = (size_t)b * CAP;
  for (int i = t; i < cb; i += 256)
    atomicAdd(&lc[((uint32_t)pb[base + i].x) >> 24], 1);
  __syncthreads();
  int c = lc[t];
  int r = (b << BSH) + t;
  if (r < N) cnt[r] = c;
  int v = c;
  v += __shfl_xor(v, 1); v += __shfl_xor(v, 2); v += __shfl_xor(v, 4);
  v += __shfl_xor(v, 8); v += __shfl_xor(v, 16); v += __shfl_xor(v, 32);
  if ((t & 63) == 0) ws[t >> 6] = v;
  __syncthreads();
  if (t == 0) bsum[b] = ws[0] + ws[1] + ws[2] + ws[3];
}

// ---------------- CSR build: scan of bucket sums (1 block) ----------------
__global__ __launch_bounds__(1024) void k_scanP(const int* __restrict__ bsum,
    int* __restrict__ boff, int* __restrict__ ptrN, int P) {
  __shared__ int ls[1024];
  int t = threadIdx.x;
  int v = (t < P) ? bsum[t] : 0;
  ls[t] = v;
  __syncthreads();
  for (int off = 1; off < 1024; off <<= 1) {
    int u = (t >= off) ? ls[t - off] : 0;
    __syncthreads();
    ls[t] += u;
    __syncthreads();
  }
  if (t < P) boff[t] = ls[t] - v;
  if (t == 1023) *ptrN = ls[1023];
}

// ---------------- CSR build: per-bucket row-offset scan ----------------
__global__ __launch_bounds__(256) void kB_ptr(const int* __restrict__ cnt,
    const int* __restrict__ boff, int* __restrict__ ptr, int N) {
  __shared__ int ls[256];
  int b = blockIdx.x;
  int t = threadIdx.x;
  int r = (b << BSH) + t;
  int v = (r < N) ? cnt[r] : 0;
  ls[t] = v;
  __syncthreads();
  for (int off = 1; off < 256; off <<= 1) {
    int u = (t >= off) ? ls[t - off] : 0;
    __syncthreads();
    ls[t] += u;
    __syncthreads();
  }
  if (r < N) ptr[r] = boff[b] + ls[t] - v;
}

// ---------------- CSR build, phase B2: within-bucket rank scatter ----------------
__global__ __launch_bounds__(256) void kB_scatter(const int* __restrict__ ccur,
    const int2* __restrict__ pb, const int* __restrict__ ptr,
    int2* __restrict__ cv, int CAP) {
  __shared__ int rk[256];
  const int b = blockIdx.x;
  rk[threadIdx.x] = 0;
  __syncthreads();
  int cb = min(ccur[b], CAP);
  size_t base = (size_t)b * CAP;
  for (int i = threadIdx.x; i < cb; i += 256) {
    int2 p2 = pb[base + i];
    int r8 = ((uint32_t)p2.x) >> 24;
    int r = (b << BSH) + r8;
    int rank = atomicAdd(&rk[r8], 1);
    cv[ptr[r] + rank] = make_int2(p2.x & 0x00FFFFFF, p2.y);
  }
}

// ---------------- LayerNorm: bf16 h row -> normalized row ----------------
// FP8OUT=1: emit fp8 e4m3 (spmm gather payload). FP8OUT=0: emit bf16.
template<int FP8OUT>
__global__ __launch_bounds__(256) void k_ln(const ushort* __restrict__ h,
    const float* __restrict__ g, const float* __restrict__ b,
    void* __restrict__ o, int n) {
  int r = (blockIdx.x * 256 + threadIdx.x) >> 6;
  int lane = threadIdx.x & 63;
  if (r >= n) return;
  ushort4 hv = *(const ushort4*)(h + (size_t)r * NHID + lane * 4);
  float v0 = b2f(hv.x), v1 = b2f(hv.y), v2 = b2f(hv.z), v3 = b2f(hv.w);
  float s = v0 + v1 + v2 + v3;
  s += __shfl_xor(s, 1); s += __shfl_xor(s, 2); s += __shfl_xor(s, 4);
  s += __shfl_xor(s, 8); s += __shfl_xor(s, 16); s += __shfl_xor(s, 32);
  float mu = s * (1.f / NHID);
  float d0 = v0 - mu, d1 = v1 - mu, d2 = v2 - mu, d3 = v3 - mu;
  float q = d0 * d0 + d1 * d1 + d2 * d2 + d3 * d3;
  q += __shfl_xor(q, 1); q += __shfl_xor(q, 2); q += __shfl_xor(q, 4);
  q += __shfl_xor(q, 8); q += __shfl_xor(q, 16); q += __shfl_xor(q, 32);
  float rs = rsqrtf(q * (1.f / NHID) + 1e-5f);
  float4 gv = *(const float4*)(g + lane * 4);
  float4 bv = *(const float4*)(b + lane * 4);
  float o0 = d0 * rs * gv.x + bv.x;
  float o1 = d1 * rs * gv.y + bv.y;
  float o2 = d2 * rs * gv.z + bv.z;
  float o3 = d3 * rs * gv.w + bv.w;
  if (FP8OUT) {
    int w = 0;
    w = __builtin_amdgcn_cvt_pk_fp8_f32(o0, o1, w, false);
    w = __builtin_amdgcn_cvt_pk_fp8_f32(o2, o3, w, true);
    ((uint32_t*)o)[(size_t)r * 64 + lane] = (uint32_t)w;
  } else {
    ushort4 t;
    t.x = f2bf(o0); t.y = f2bf(o1); t.z = f2bf(o2); t.w = f2bf(o3);
    *(ushort4*)((ushort*)o + (size_t)r * NHID + lane * 4) = t;
  }
}

// ---------------- SpMM: agg[i] = sum_e val[e] * t8[col[e]]  (fp8 gather) ----------------
// One wave/row; 4 edges/iter (quarter lane>>4), 16B/lane uint4 gathers (16 lanes
// span the 256B fp8 row), unroll 4 for deep MLP. Packed pk_fma accumulate.
__global__ __launch_bounds__(256) void k_spmm(const int* __restrict__ ptr,
    const int2* __restrict__ cv, const uint32_t* __restrict__ t8,
    ushort* __restrict__ agg, int n) {
  int r = (blockIdx.x * 256 + threadIdx.x) >> 6;
  int lane = threadIdx.x & 63;
  if (r >= n) return;
  int s = ptr[r], e = ptr[r + 1];
  int cnt = e - s;
  int q = lane >> 4;
  int seg = lane & 15;
  f32x2 acc2[8];
#pragma unroll
  for (int j = 0; j < 8; j++) acc2[j] = (f32x2){0.f, 0.f};

  for (int base = 0; base < cnt; base += 64) {
    int idx = s + base + lane;
    int ec = 0; float ev = 0.f;
    if (idx < e) {
      int2 p2 = cv[idx];
      ec = p2.x;
      ev = __uint_as_float((uint32_t)p2.y);
    }
    int lim = min(64, cnt - base);
#pragma unroll 4
    for (int i = 0; i < lim; i += 4) {
      int a = i + q;                    // a <= 63 always
      int c = __shfl(ec, a);
      float v = __shfl(ev, a);          // 0 for out-of-range edges
      f32x2 vv = {v, v};
      uint4 tv = *(const uint4*)(t8 + (size_t)c * 64 + seg * 4);
      f32x2 p;
      p = __builtin_amdgcn_cvt_pk_f32_fp8(tv.x, false);
      acc2[0] = __builtin_elementwise_fma(p, vv, acc2[0]);
      p = __builtin_amdgcn_cvt_pk_f32_fp8(tv.x, true);
      acc2[1] = __builtin_elementwise_fma(p, vv, acc2[1]);
      p = __builtin_amdgcn_cvt_pk_f32_fp8(tv.y, false);
      acc2[2] = __builtin_elementwise_fma(p, vv, acc2[2]);
      p = __builtin_amdgcn_cvt_pk_f32_fp8(tv.y, true);
      acc2[3] = __builtin_elementwise_fma(p, vv, acc2[3]);
      p = __builtin_amdgcn_cvt_pk_f32_fp8(tv.z, false);
      acc2[4] = __builtin_elementwise_fma(p, vv, acc2[4]);
      p = __builtin_amdgcn_cvt_pk_f32_fp8(tv.z, true);
      acc2[5] = __builtin_elementwise_fma(p, vv, acc2[5]);
      p = __builtin_amdgcn_cvt_pk_f32_fp8(tv.w, false);
      acc2[6] = __builtin_elementwise_fma(p, vv, acc2[6]);
      p = __builtin_amdgcn_cvt_pk_f32_fp8(tv.w, true);
      acc2[7] = __builtin_elementwise_fma(p, vv, acc2[7]);
    }
  }

  float accs[16];
#pragma unroll
  for (int j = 0; j < 8; j++) { accs[2 * j] = acc2[j][0]; accs[2 * j + 1] = acc2[j][1]; }
#pragma unroll
  for (int j = 0; j < 16; j++) {
    accs[j] += __shfl_xor(accs[j], 16);
    accs[j] += __shfl_xor(accs[j], 32);
  }
  if (q == 0) {
    short8 o0, o1;
#pragma unroll
    for (int j = 0; j < 8; j++) { o0[j] = (short)f2bf(accs[j]); o1[j] = (short)f2bf(accs[8 + j]); }
    *(short8*)(agg + (size_t)r * NHID + seg * 16) = o0;
    *(short8*)(agg + (size_t)r * NHID + seg * 16 + 8) = o1;
  }
}

// ---------------- MFMA GEMM: C = A(MxK,bf16) @ B(NxK,bf16)^T, fused epilogue ----------------
// H is bf16. MODE 0: H = relu(C+bias); 1: H += relu(C+bias); 2: H += C+bias
// Grid is (col_tiles, row_tiles): col-tiles of the same A rows are adjacent in
// dispatch order -> second col-tile hits A in L2/L3 instead of HBM.
template<int MODE>
__global__ __launch_bounds__(256) void k_gemm(const ushort* __restrict__ A,
    const ushort* __restrict__ B, const float* __restrict__ bias,
    ushort* __restrict__ H, int M, int K) {
  __shared__ ushort As[128 * 32];
  __shared__ ushort Bs[128 * 32];
  const int t = threadIdx.x;
  const int lane = t & 63;
  const int wid = t >> 6;
  const int brow = blockIdx.y * 128;
  const int bcol = blockIdx.x * 128;
  const int wr = (wid >> 1) * 64;
  const int wc = (wid & 1) * 64;
  const int l15 = lane & 15, hi = lane >> 4;
  const f32x4 z4 = {0.f, 0.f, 0.f, 0.f};
  f32x4 acc[4][4];
  for (int m = 0; m < 4; m++)
    for (int n = 0; n < 4; n++) acc[m][n] = z4;

  for (int k0 = 0; k0 < K; k0 += 32) {
    __syncthreads();
#pragma unroll
    for (int c = 0; c < 2; c++) {
      int s = c * 256 + t;
      int r = s >> 2;
      int kk = (s & 3) * 8;
      int gr = brow + r; gr = gr < M ? gr : M - 1;
      const ushort* ga = A + (size_t)gr * K + (k0 + kk);
      __builtin_amdgcn_global_load_lds((const __attribute__((address_space(1))) void*)ga,
          (__attribute__((address_space(3))) void*)(As + s * 8), 16, 0, 0);
      const ushort* gb = B + (size_t)(bcol + r) * K + (k0 + kk);
      __builtin_amdgcn_global_load_lds((const __attribute__((address_space(1))) void*)gb,
          (__attribute__((address_space(3))) void*)(Bs + s * 8), 16, 0, 0);
    }
    __syncthreads();
    short8 af[4], bf[4];
#pragma unroll
    for (int m = 0; m < 4; m++)
      af[m] = *(const short8*)(As + (wr + m * 16 + l15) * 32 + hi * 8);
#pragma unroll
    for (int n = 0; n < 4; n++)
      bf[n] = *(const short8*)(Bs + (wc + n * 16 + l15) * 32 + hi * 8);
#pragma unroll
    for (int m = 0; m < 4; m++)
#pragma unroll
      for (int n = 0; n < 4; n++)
        acc[m][n] = __builtin_amdgcn_mfma_f32_16x16x32_bf16(af[m], bf[n], acc[m][n], 0, 0, 0);
  }

#pragma unroll
  for (int m = 0; m < 4; m++) {
    int gr0 = brow + wr + m * 16 + hi * 4;
#pragma unroll
    for (int n = 0; n < 4; n++) {
      int gc = bcol + wc + n * 16 + l15;
      float bv = bias[gc];
#pragma unroll
      for (int j = 0; j < 4; j++) {
        int gr = gr0 + j;
        if (gr < M) {
          size_t idx = (size_t)gr * NHID + gc;
          float v = acc[m][n][j] + bv;
          if (MODE == 0)      H[idx] = f2bf(fmaxf(v, 0.f));
          else if (MODE == 1) H[idx] = f2bf(b2f(H[idx]) + fmaxf(v, 0.f));
          else                H[idx] = f2bf(b2f(H[idx]) + v);
        }
      }
    }
  }
}

// ---------------- output GEMM: z = Anorm @ Wo^T + ob  (skinny N=40, MFMA) ----------------
__global__ __launch_bounds__(256) void k_ogemm(const ushort* __restrict__ A,
    const ushort* __restrict__ Bw, const float* __restrict__ ob,
    float* __restrict__ z, int M) {
  __shared__ ushort As[256 * 32];
  __shared__ ushort Bs[NCPAD * 264];
  const int t = threadIdx.x;
  const int lane = t & 63;
  const int wid = t >> 6;
  const int brow = blockIdx.x * 256;
  const int wr = wid * 64;
  const int l15 = lane & 15, hi = lane >> 4;
  const f32x4 z4 = {0.f, 0.f, 0.f, 0.f};
  f32x4 acc[4][3];
#pragma unroll
  for (int m = 0; m < 4; m++)
#pragma unroll
    for (int n = 0; n < 3; n++) acc[m][n] = z4;

  for (int i = t; i < NCPAD * 33; i += 256) {
    int r = i / 33, cc = i % 33;
    if (cc < 32)
      *(short8*)(Bs + r * 264 + cc * 8) = *(const short8*)(Bw + r * 256 + cc * 8);
  }

  for (int k0 = 0; k0 < 256; k0 += 32) {
    __syncthreads();
#pragma unroll
    for (int c = 0; c < 4; c++) {
      int s = c * 256 + t;
      int r = s >> 2;
      int kk = (s & 3) * 8;
      int gr = brow + r; gr = gr < M ? gr : M - 1;
      const ushort* ga = A + (size_t)gr * NHID + (k0 + kk);
      __builtin_amdgcn_global_load_lds((const __attribute__((address_space(1))) void*)ga,
          (__attribute__((address_space(3))) void*)(As + s * 8), 16, 0, 0);
    }
    __syncthreads();
    short8 af[4], bf[3];
#pragma unroll
    for (int m = 0; m < 4; m++)
      af[m] = *(const short8*)(As + (wr + m * 16 + l15) * 32 + hi * 8);
#pragma unroll
    for (int n = 0; n < 3; n++)
      bf[n] = *(const short8*)(Bs + (n * 16 + l15) * 264 + k0 + hi * 8);
#pragma unroll
    for (int m = 0; m < 4; m++)
#pragma unroll
      for (int n = 0; n < 3; n++)
        acc[m][n] = __builtin_amdgcn_mfma_f32_16x16x32_bf16(af[m], bf[n], acc[m][n], 0, 0, 0);
  }

#pragma unroll
  for (int m = 0; m < 4; m++) {
    int gr0 = brow + wr + m * 16 + hi * 4;
#pragma unroll
    for (int n = 0; n < 3; n++) {
      int gc = n * 16 + l15;
      if (gc < NCLS) {
        float bv = ob[gc];
#pragma unroll
        for (int j = 0; j < 4; j++) {
          int gr = gr0 + j;
          if (gr < M) z[(size_t)gr * NCLS + gc] = acc[m][n][j] + bv;
        }
      }
    }
  }
}

extern "C" void kernel_launch(void* const* d_in, const int* in_sizes, int n_in,
                              void* d_out, int out_size, void* d_ws, size_t ws_size,
                              hipStream_t stream) {
  const float* x     = (const float*)d_in[0];
  const int*   row   = (const int*)d_in[1];
  const int*   col   = (const int*)d_in[2];
  const float* val   = (const float*)d_in[3];
  const float* inW   = (const float*)d_in[4];
  const float* inB   = (const float*)d_in[5];
  const float* convW = (const float*)d_in[6];
  const float* convB = (const float*)d_in[7];
  const float* lnG   = (const float*)d_in[8];
  const float* lnB   = (const float*)d_in[9];
  const float* outG  = (const float*)d_in[10];
  const float* outB  = (const float*)d_in[11];
  const float* outW  = (const float*)d_in[12];
  const float* outb  = (const float*)d_in[13];
  const int N = in_sizes[0] / NFEAT;
  const int E = in_sizes[1];
  float* z = (float*)d_out;

  const int P   = (N + 255) >> BSH;
  const int CAP = ((((E + P - 1) / P) * 5 / 4 + 256) + 15) & ~15;

  char* wsp = (char*)d_ws;
  size_t off = 0;
  auto alloc = [&](size_t bytes) {
    void* p = wsp + off;
    off += (bytes + 255) & ~(size_t)255;
    return p;
  };
  ushort*   h   = (ushort*)alloc((size_t)N * NHID * 2);   // bf16 residual stream
  ushort*   tb  = (ushort*)alloc((size_t)N * NHID * 2);
  ushort*   ab  = (ushort*)alloc((size_t)N * NHID * 2);
  uint32_t* t8  = (uint32_t*)alloc((size_t)N * 64 * 4);   // fp8 LN output (256B/row)
  ushort*   xb  = (ushort*)alloc((size_t)N * KPAD * 2);   // also CSR scratch after input gemm
  ushort*   wbi = (ushort*)alloc((size_t)NHID * KPAD * 2);
  ushort*   wbc = (ushort*)alloc((size_t)NLAY * NHID * NHID * 2);
  ushort*   wbo = (ushort*)alloc((size_t)NCPAD * NHID * 2);
  int*   cnt  = (int*)alloc((size_t)N * 4);
  int*   ptr  = (int*)alloc((size_t)(N + 1) * 4);
  int*   ccur = (int*)alloc((size_t)P * 4);
  int*   bsum = (int*)alloc((size_t)P * 4);
  int*   boff = (int*)alloc((size_t)P * 4);
  int2*  cv   = (int2*)alloc((size_t)E * 8);
  int2*  pb   = (int2*)xb;   // aliases xb (dead after input gemm)

  // bf16 casts
  {
    int tot = N * (KPAD >> 2);
    k_cast_pad<<<(tot + 255) / 256, 256, 0, stream>>>(x, xb, N, NFEAT, KPAD);
    tot = NHID * (KPAD >> 2);
    k_cast_pad<<<(tot + 255) / 256, 256, 0, stream>>>(inW, wbi, NHID, NFEAT, KPAD);
    tot = NLAY * NHID * (NHID >> 2);
    k_cast_pad<<<(tot + 255) / 256, 256, 0, stream>>>(convW, wbc, NLAY * NHID, NHID, NHID);
    hipMemsetAsync(wbo, 0, (size_t)NCPAD * NHID * 2, stream);
    tot = NCLS * (NHID >> 2);
    k_cast_pad<<<(tot + 255) / 256, 256, 0, stream>>>(outW, wbo, NCLS, NHID, NHID);
  }

  // input layer first (so xb can be reused as CSR scratch)
  // grid: (col_tiles, row_tiles) -> A-reuse between adjacent col-tile blocks
  dim3 gg(NHID / 128, (N + 127) / 128);
  k_gemm<0><<<gg, 256, 0, stream>>>(xb, wbi, inB, h, N, KPAD);

  // CSR build: locality-binned two-phase counting sort, hierarchical scan
  hipMemsetAsync(ccur, 0, (size_t)P * 4, stream);
  kA_scatter<<<(E + CHUNK - 1) / CHUNK, 256, 0, stream>>>(row, col, val, ccur, pb, E, P, CAP);
  kB_cnt<<<P, 256, 0, stream>>>(ccur, pb, cnt, bsum, N, CAP);
  k_scanP<<<1, 1024, 0, stream>>>(bsum, boff, ptr + N, P);
  kB_ptr<<<P, 256, 0, stream>>>(cnt, boff, ptr, N);
  kB_scatter<<<P, 256, 0, stream>>>(ccur, pb, ptr, cv, CAP);

  int nwb = (N + 3) / 4;
  for (int i = 0; i < NLAY; i++) {
    k_ln<1><<<nwb, 256, 0, stream>>>(h, lnG + i * NHID, lnB + i * NHID, t8, N);
    k_spmm<<<nwb, 256, 0, stream>>>(ptr, cv, t8, ab, N);
    if (i < NLAY - 1)
      k_gemm<1><<<gg, 256, 0, stream>>>(ab, wbc + (size_t)i * NHID * NHID,
                                        convB + i * NHID, h, N, NHID);
    else
      k_gemm<2><<<gg, 256, 0, stream>>>(ab, wbc + (size_t)i * NHID * NHID,
                                        convB + i * NHID, h, N, NHID);
  }

  k_ln<0><<<nwb, 256, 0, stream>>>(h, outG, outB, tb, N);
  k_ogemm<<<(N + 255) / 256, 256, 0, stream>>>(tb, wbo, outb, z, N);
}

// Round 12
// 1246.551 us; speedup vs baseline: 1.3115x; 1.0099x over previous
//
#include <hip/hip_runtime.h>
#include <stdint.h>

#define NFEAT 500
#define KPAD  512
#define NHID  256
#define NCLS  40
#define NCPAD 48
#define NLAY  5
#define BSH   8      // coarse bucket = row >> 8
#define CHUNK 8192   // edges per kA block

typedef __attribute__((ext_vector_type(8))) short short8;
typedef __attribute__((ext_vector_type(4))) float f32x4;
typedef __attribute__((ext_vector_type(2))) float f32x2;

__device__ __forceinline__ ushort f2bf(float f) {
  uint32_t u = __float_as_uint(f);
  u += 0x7fffu + ((u >> 16) & 1u);
  return (ushort)(u >> 16);
}
__device__ __forceinline__ float b2f(ushort h) {
  return __uint_as_float(((uint32_t)h) << 16);
}

// ---------------- casts (fp32 -> bf16, with K padding) ----------------
__global__ __launch_bounds__(256) void k_cast_pad(const float* __restrict__ src,
    ushort* __restrict__ dst, int rows, int scol, int dcol) {
  int id = blockIdx.x * 256 + threadIdx.x;
  int cpr = dcol >> 2;
  if (id >= rows * cpr) return;
  int r = id / cpr;
  int c = (id % cpr) * 4;
  float4 v;
  if (c + 3 < scol) {
    v = *(const float4*)(src + (size_t)r * scol + c);
  } else {
    v.x = (c + 0 < scol) ? src[(size_t)r * scol + c + 0] : 0.f;
    v.y = (c + 1 < scol) ? src[(size_t)r * scol + c + 1] : 0.f;
    v.z = (c + 2 < scol) ? src[(size_t)r * scol + c + 2] : 0.f;
    v.w = (c + 3 < scol) ? src[(size_t)r * scol + c + 3] : 0.f;
  }
  ushort4 o;
  o.x = f2bf(v.x); o.y = f2bf(v.y); o.z = f2bf(v.z); o.w = f2bf(v.w);
  *(ushort4*)(dst + (size_t)r * dcol + c) = o;
}

// ---------------- CSR build, phase A: coarse bucket scatter ----------------
__global__ __launch_bounds__(256) void kA_scatter(const int* __restrict__ row,
    const int* __restrict__ col, const float* __restrict__ val,
    int* __restrict__ ccur, int2* __restrict__ pb, int E, int P, int CAP) {
  __shared__ int lh[512];
  const int t = threadIdx.x;
  const int b0 = blockIdx.x * CHUNK;
  for (int i = t; i < P; i += 256) lh[i] = 0;
  __syncthreads();
#pragma unroll 4
  for (int i = 0; i < CHUNK / 256; i++) {
    int idx = b0 + i * 256 + t;
    if (idx < E) atomicAdd(&lh[row[idx] >> BSH], 1);
  }
  __syncthreads();
  for (int i = t; i < P; i += 256) {
    int c = lh[i];
    lh[i] = (c > 0) ? atomicAdd(&ccur[i], c) : 0;
  }
  __syncthreads();
#pragma unroll 4
  for (int i = 0; i < CHUNK / 256; i++) {
    int idx = b0 + i * 256 + t;
    if (idx < E) {
      int r = row[idx];
      int p = r >> BSH;
      int pos = atomicAdd(&lh[p], 1);
      if (pos < CAP)
        pb[(size_t)p * CAP + pos] =
            make_int2(col[idx] | ((r & 255) << 24), __float_as_int(val[idx]));
    }
  }
}

// ---------------- CSR build, phase B1: per-row counts + bucket sums ----------------
__global__ __launch_bounds__(256) void kB_cnt(const int* __restrict__ ccur,
    const int2* __restrict__ pb, int* __restrict__ cnt, int* __restrict__ bsum,
    int N, int CAP) {
  __shared__ int lc[256];
  __shared__ int ws[4];
  const int b = blockIdx.x;
  const int t = threadIdx.x;
  lc[t] = 0;
  __syncthreads();
  int cb = min(ccur[b], CAP);
  size_t base = (size_t)b * CAP;
  for (int i = t; i < cb; i += 256)
    atomicAdd(&lc[((uint32_t)pb[base + i].x) >> 24], 1);
  __syncthreads();
  int c = lc[t];
  int r = (b << BSH) + t;
  if (r < N) cnt[r] = c;
  int v = c;
  v += __shfl_xor(v, 1); v += __shfl_xor(v, 2); v += __shfl_xor(v, 4);
  v += __shfl_xor(v, 8); v += __shfl_xor(v, 16); v += __shfl_xor(v, 32);
  if ((t & 63) == 0) ws[t >> 6] = v;
  __syncthreads();
  if (t == 0) bsum[b] = ws[0] + ws[1] + ws[2] + ws[3];
}

// ---------------- CSR build: scan of bucket sums (1 block) ----------------
__global__ __launch_bounds__(1024) void k_scanP(const int* __restrict__ bsum,
    int* __restrict__ boff, int* __restrict__ ptrN, int P) {
  __shared__ int ls[1024];
  int t = threadIdx.x;
  int v = (t < P) ? bsum[t] : 0;
  ls[t] = v;
  __syncthreads();
  for (int off = 1; off < 1024; off <<= 1) {
    int u = (t >= off) ? ls[t - off] : 0;
    __syncthreads();
    ls[t] += u;
    __syncthreads();
  }
  if (t < P) boff[t] = ls[t] - v;
  if (t == 1023) *ptrN = ls[1023];
}

// ---------------- CSR build: per-bucket row-offset scan ----------------
__global__ __launch_bounds__(256) void kB_ptr(const int* __restrict__ cnt,
    const int* __restrict__ boff, int* __restrict__ ptr, int N) {
  __shared__ int ls[256];
  int b = blockIdx.x;
  int t = threadIdx.x;
  int r = (b << BSH) + t;
  int v = (r < N) ? cnt[r] : 0;
  ls[t] = v;
  __syncthreads();
  for (int off = 1; off < 256; off <<= 1) {
    int u = (t >= off) ? ls[t - off] : 0;
    __syncthreads();
    ls[t] += u;
    __syncthreads();
  }
  if (r < N) ptr[r] = boff[b] + ls[t] - v;
}

// ---------------- CSR build, phase B2: within-bucket rank scatter ----------------
__global__ __launch_bounds__(256) void kB_scatter(const int* __restrict__ ccur,
    const int2* __restrict__ pb, const int* __restrict__ ptr,
    int2* __restrict__ cv, int CAP) {
  __shared__ int rk[256];
  const int b = blockIdx.x;
  rk[threadIdx.x] = 0;
  __syncthreads();
  int cb = min(ccur[b], CAP);
  size_t base = (size_t)b * CAP;
  for (int i = threadIdx.x; i < cb; i += 256) {
    int2 p2 = pb[base + i];
    int r8 = ((uint32_t)p2.x) >> 24;
    int r = (b << BSH) + r8;
    int rank = atomicAdd(&rk[r8], 1);
    cv[ptr[r] + rank] = make_int2(p2.x & 0x00FFFFFF, p2.y);
  }
}

// ---------------- LayerNorm: bf16 h row -> normalized row ----------------
// FP8OUT=1: emit fp8 e4m3 (spmm gather payload). FP8OUT=0: emit bf16.
template<int FP8OUT>
__global__ __launch_bounds__(256) void k_ln(const ushort* __restrict__ h,
    const float* __restrict__ g, const float* __restrict__ b,
    void* __restrict__ o, int n) {
  int r = (blockIdx.x * 256 + threadIdx.x) >> 6;
  int lane = threadIdx.x & 63;
  if (r >= n) return;
  ushort4 hv = *(const ushort4*)(h + (size_t)r * NHID + lane * 4);
  float v0 = b2f(hv.x), v1 = b2f(hv.y), v2 = b2f(hv.z), v3 = b2f(hv.w);
  float s = v0 + v1 + v2 + v3;
  s += __shfl_xor(s, 1); s += __shfl_xor(s, 2); s += __shfl_xor(s, 4);
  s += __shfl_xor(s, 8); s += __shfl_xor(s, 16); s += __shfl_xor(s, 32);
  float mu = s * (1.f / NHID);
  float d0 = v0 - mu, d1 = v1 - mu, d2 = v2 - mu, d3 = v3 - mu;
  float q = d0 * d0 + d1 * d1 + d2 * d2 + d3 * d3;
  q += __shfl_xor(q, 1); q += __shfl_xor(q, 2); q += __shfl_xor(q, 4);
  q += __shfl_xor(q, 8); q += __shfl_xor(q, 16); q += __shfl_xor(q, 32);
  float rs = rsqrtf(q * (1.f / NHID) + 1e-5f);
  float4 gv = *(const float4*)(g + lane * 4);
  float4 bv = *(const float4*)(b + lane * 4);
  float o0 = d0 * rs * gv.x + bv.x;
  float o1 = d1 * rs * gv.y + bv.y;
  float o2 = d2 * rs * gv.z + bv.z;
  float o3 = d3 * rs * gv.w + bv.w;
  if (FP8OUT) {
    int w = 0;
    w = __builtin_amdgcn_cvt_pk_fp8_f32(o0, o1, w, false);
    w = __builtin_amdgcn_cvt_pk_fp8_f32(o2, o3, w, true);
    ((uint32_t*)o)[(size_t)r * 64 + lane] = (uint32_t)w;
  } else {
    ushort4 t;
    t.x = f2bf(o0); t.y = f2bf(o1); t.z = f2bf(o2); t.w = f2bf(o3);
    *(ushort4*)((ushort*)o + (size_t)r * NHID + lane * 4) = t;
  }
}

// ---------------- SpMM: agg[i] = sum_e val[e] * t8[col[e]]  (fp8 gather) ----------------
__global__ __launch_bounds__(256) void k_spmm(const int* __restrict__ ptr,
    const int2* __restrict__ cv, const uint32_t* __restrict__ t8,
    ushort* __restrict__ agg, int n) {
  int r = (blockIdx.x * 256 + threadIdx.x) >> 6;
  int lane = threadIdx.x & 63;
  if (r >= n) return;
  int s = ptr[r], e = ptr[r + 1];
  int cnt = e - s;
  int q = lane >> 4;
  int seg = lane & 15;
  f32x2 acc2[8];
#pragma unroll
  for (int j = 0; j < 8; j++) acc2[j] = (f32x2){0.f, 0.f};

  for (int base = 0; base < cnt; base += 64) {
    int idx = s + base + lane;
    int ec = 0; float ev = 0.f;
    if (idx < e) {
      int2 p2 = cv[idx];
      ec = p2.x;
      ev = __uint_as_float((uint32_t)p2.y);
    }
    int lim = min(64, cnt - base);
#pragma unroll 4
    for (int i = 0; i < lim; i += 4) {
      int a = i + q;                    // a <= 63 always
      int c = __shfl(ec, a);
      float v = __shfl(ev, a);          // 0 for out-of-range edges
      f32x2 vv = {v, v};
      uint4 tv = *(const uint4*)(t8 + (size_t)c * 64 + seg * 4);
      f32x2 p;
      p = __builtin_amdgcn_cvt_pk_f32_fp8(tv.x, false);
      acc2[0] = __builtin_elementwise_fma(p, vv, acc2[0]);
      p = __builtin_amdgcn_cvt_pk_f32_fp8(tv.x, true);
      acc2[1] = __builtin_elementwise_fma(p, vv, acc2[1]);
      p = __builtin_amdgcn_cvt_pk_f32_fp8(tv.y, false);
      acc2[2] = __builtin_elementwise_fma(p, vv, acc2[2]);
      p = __builtin_amdgcn_cvt_pk_f32_fp8(tv.y, true);
      acc2[3] = __builtin_elementwise_fma(p, vv, acc2[3]);
      p = __builtin_amdgcn_cvt_pk_f32_fp8(tv.z, false);
      acc2[4] = __builtin_elementwise_fma(p, vv, acc2[4]);
      p = __builtin_amdgcn_cvt_pk_f32_fp8(tv.z, true);
      acc2[5] = __builtin_elementwise_fma(p, vv, acc2[5]);
      p = __builtin_amdgcn_cvt_pk_f32_fp8(tv.w, false);
      acc2[6] = __builtin_elementwise_fma(p, vv, acc2[6]);
      p = __builtin_amdgcn_cvt_pk_f32_fp8(tv.w, true);
      acc2[7] = __builtin_elementwise_fma(p, vv, acc2[7]);
    }
  }

  float accs[16];
#pragma unroll
  for (int j = 0; j < 8; j++) { accs[2 * j] = acc2[j][0]; accs[2 * j + 1] = acc2[j][1]; }
#pragma unroll
  for (int j = 0; j < 16; j++) {
    accs[j] += __shfl_xor(accs[j], 16);
    accs[j] += __shfl_xor(accs[j], 32);
  }
  if (q == 0) {
    short8 o0, o1;
#pragma unroll
    for (int j = 0; j < 8; j++) { o0[j] = (short)f2bf(accs[j]); o1[j] = (short)f2bf(accs[8 + j]); }
    *(short8*)(agg + (size_t)r * NHID + seg * 16) = o0;
    *(short8*)(agg + (size_t)r * NHID + seg * 16 + 8) = o1;
  }
}

// ---------------- MFMA GEMM: C = A(MxK,bf16) @ B(NxK,bf16)^T, fused epilogue ----------------
// H is bf16. MODE 0: H = relu(C+bias); 1: H += relu(C+bias); 2: H += C+bias
// 1-D grid with XCD-pair swizzle: in each group of 16 consecutive block ids,
// ids o and o+8 (same XCD under round-robin dispatch) are (bcol0, bcol1) of the
// SAME 128 A-rows -> the A tile is L2-hot on that XCD for the second block.
template<int MODE>
__global__ __launch_bounds__(256) void k_gemm(const ushort* __restrict__ A,
    const ushort* __restrict__ B, const float* __restrict__ bias,
    ushort* __restrict__ H, int M, int K) {
  const int RT = (M + 127) >> 7;
  const int g = blockIdx.x >> 4;
  const int o = blockIdx.x & 15;
  const int rowi = g * 8 + (o & 7);
  if (rowi >= RT) return;
  const int brow = rowi * 128;
  const int bcol = (o >> 3) * 128;
  __shared__ ushort As[128 * 32];
  __shared__ ushort Bs[128 * 32];
  const int t = threadIdx.x;
  const int lane = t & 63;
  const int wid = t >> 6;
  const int wr = (wid >> 1) * 64;
  const int wc = (wid & 1) * 64;
  const int l15 = lane & 15, hi = lane >> 4;
  const f32x4 z4 = {0.f, 0.f, 0.f, 0.f};
  f32x4 acc[4][4];
  for (int m = 0; m < 4; m++)
    for (int n = 0; n < 4; n++) acc[m][n] = z4;

  for (int k0 = 0; k0 < K; k0 += 32) {
    __syncthreads();
#pragma unroll
    for (int c = 0; c < 2; c++) {
      int s = c * 256 + t;
      int r = s >> 2;
      int kk = (s & 3) * 8;
      int gr = brow + r; gr = gr < M ? gr : M - 1;
      const ushort* ga = A + (size_t)gr * K + (k0 + kk);
      __builtin_amdgcn_global_load_lds((const __attribute__((address_space(1))) void*)ga,
          (__attribute__((address_space(3))) void*)(As + s * 8), 16, 0, 0);
      const ushort* gb = B + (size_t)(bcol + r) * K + (k0 + kk);
      __builtin_amdgcn_global_load_lds((const __attribute__((address_space(1))) void*)gb,
          (__attribute__((address_space(3))) void*)(Bs + s * 8), 16, 0, 0);
    }
    __syncthreads();
    short8 af[4], bf[4];
#pragma unroll
    for (int m = 0; m < 4; m++)
      af[m] = *(const short8*)(As + (wr + m * 16 + l15) * 32 + hi * 8);
#pragma unroll
    for (int n = 0; n < 4; n++)
      bf[n] = *(const short8*)(Bs + (wc + n * 16 + l15) * 32 + hi * 8);
#pragma unroll
    for (int m = 0; m < 4; m++)
#pragma unroll
      for (int n = 0; n < 4; n++)
        acc[m][n] = __builtin_amdgcn_mfma_f32_16x16x32_bf16(af[m], bf[n], acc[m][n], 0, 0, 0);
  }

#pragma unroll
  for (int m = 0; m < 4; m++) {
    int gr0 = brow + wr + m * 16 + hi * 4;
#pragma unroll
    for (int n = 0; n < 4; n++) {
      int gc = bcol + wc + n * 16 + l15;
      float bv = bias[gc];
#pragma unroll
      for (int j = 0; j < 4; j++) {
        int gr = gr0 + j;
        if (gr < M) {
          size_t idx = (size_t)gr * NHID + gc;
          float v = acc[m][n][j] + bv;
          if (MODE == 0)      H[idx] = f2bf(fmaxf(v, 0.f));
          else if (MODE == 1) H[idx] = f2bf(b2f(H[idx]) + fmaxf(v, 0.f));
          else                H[idx] = f2bf(b2f(H[idx]) + v);
        }
      }
    }
  }
}

// ---------------- output GEMM: z = Anorm @ Wo^T + ob  (skinny N=40, MFMA) ----------------
__global__ __launch_bounds__(256) void k_ogemm(const ushort* __restrict__ A,
    const ushort* __restrict__ Bw, const float* __restrict__ ob,
    float* __restrict__ z, int M) {
  __shared__ ushort As[256 * 32];
  __shared__ ushort Bs[NCPAD * 264];
  const int t = threadIdx.x;
  const int lane = t & 63;
  const int wid = t >> 6;
  const int brow = blockIdx.x * 256;
  const int wr = wid * 64;
  const int l15 = lane & 15, hi = lane >> 4;
  const f32x4 z4 = {0.f, 0.f, 0.f, 0.f};
  f32x4 acc[4][3];
#pragma unroll
  for (int m = 0; m < 4; m++)
#pragma unroll
    for (int n = 0; n < 3; n++) acc[m][n] = z4;

  for (int i = t; i < NCPAD * 33; i += 256) {
    int r = i / 33, cc = i % 33;
    if (cc < 32)
      *(short8*)(Bs + r * 264 + cc * 8) = *(const short8*)(Bw + r * 256 + cc * 8);
  }

  for (int k0 = 0; k0 < 256; k0 += 32) {
    __syncthreads();
#pragma unroll
    for (int c = 0; c < 4; c++) {
      int s = c * 256 + t;
      int r = s >> 2;
      int kk = (s & 3) * 8;
      int gr = brow + r; gr = gr < M ? gr : M - 1;
      const ushort* ga = A + (size_t)gr * NHID + (k0 + kk);
      __builtin_amdgcn_global_load_lds((const __attribute__((address_space(1))) void*)ga,
          (__attribute__((address_space(3))) void*)(As + s * 8), 16, 0, 0);
    }
    __syncthreads();
    short8 af[4], bf[3];
#pragma unroll
    for (int m = 0; m < 4; m++)
      af[m] = *(const short8*)(As + (wr + m * 16 + l15) * 32 + hi * 8);
#pragma unroll
    for (int n = 0; n < 3; n++)
      bf[n] = *(const short8*)(Bs + (n * 16 + l15) * 264 + k0 + hi * 8);
#pragma unroll
    for (int m = 0; m < 4; m++)
#pragma unroll
      for (int n = 0; n < 3; n++)
        acc[m][n] = __builtin_amdgcn_mfma_f32_16x16x32_bf16(af[m], bf[n], acc[m][n], 0, 0, 0);
  }

#pragma unroll
  for (int m = 0; m < 4; m++) {
    int gr0 = brow + wr + m * 16 + hi * 4;
#pragma unroll
    for (int n = 0; n < 3; n++) {
      int gc = n * 16 + l15;
      if (gc < NCLS) {
        float bv = ob[gc];
#pragma unroll
        for (int j = 0; j < 4; j++) {
          int gr = gr0 + j;
          if (gr < M) z[(size_t)gr * NCLS + gc] = acc[m][n][j] + bv;
        }
      }
    }
  }
}

extern "C" void kernel_launch(void* const* d_in, const int* in_sizes, int n_in,
                              void* d_out, int out_size, void* d_ws, size_t ws_size,
                              hipStream_t stream) {
  const float* x     = (const float*)d_in[0];
  const int*   row   = (const int*)d_in[1];
  const int*   col   = (const int*)d_in[2];
  const float* val   = (const float*)d_in[3];
  const float* inW   = (const float*)d_in[4];
  const float* inB   = (const float*)d_in[5];
  const float* convW = (const float*)d_in[6];
  const float* convB = (const float*)d_in[7];
  const float* lnG   = (const float*)d_in[8];
  const float* lnB   = (const float*)d_in[9];
  const float* outG  = (const float*)d_in[10];
  const float* outB  = (const float*)d_in[11];
  const float* outW  = (const float*)d_in[12];
  const float* outb  = (const float*)d_in[13];
  const int N = in_sizes[0] / NFEAT;
  const int E = in_sizes[1];
  float* z = (float*)d_out;

  const int P   = (N + 255) >> BSH;
  const int CAP = ((((E + P - 1) / P) * 5 / 4 + 256) + 15) & ~15;

  char* wsp = (char*)d_ws;
  size_t off = 0;
  auto alloc = [&](size_t bytes) {
    void* p = wsp + off;
    off += (bytes + 255) & ~(size_t)255;
    return p;
  };
  ushort*   h   = (ushort*)alloc((size_t)N * NHID * 2);   // bf16 residual stream
  ushort*   tb  = (ushort*)alloc((size_t)N * NHID * 2);
  ushort*   ab  = (ushort*)alloc((size_t)N * NHID * 2);
  uint32_t* t8  = (uint32_t*)alloc((size_t)N * 64 * 4);   // fp8 LN output (256B/row)
  ushort*   xb  = (ushort*)alloc((size_t)N * KPAD * 2);   // also CSR scratch after input gemm
  ushort*   wbi = (ushort*)alloc((size_t)NHID * KPAD * 2);
  ushort*   wbc = (ushort*)alloc((size_t)NLAY * NHID * NHID * 2);
  ushort*   wbo = (ushort*)alloc((size_t)NCPAD * NHID * 2);
  int*   cnt  = (int*)alloc((size_t)N * 4);
  int*   ptr  = (int*)alloc((size_t)(N + 1) * 4);
  int*   ccur = (int*)alloc((size_t)P * 4);
  int*   bsum = (int*)alloc((size_t)P * 4);
  int*   boff = (int*)alloc((size_t)P * 4);
  int2*  cv   = (int2*)alloc((size_t)E * 8);
  int2*  pb   = (int2*)xb;   // aliases xb (dead after input gemm)

  // bf16 casts
  {
    int tot = N * (KPAD >> 2);
    k_cast_pad<<<(tot + 255) / 256, 256, 0, stream>>>(x, xb, N, NFEAT, KPAD);
    tot = NHID * (KPAD >> 2);
    k_cast_pad<<<(tot + 255) / 256, 256, 0, stream>>>(inW, wbi, NHID, NFEAT, KPAD);
    tot = NLAY * NHID * (NHID >> 2);
    k_cast_pad<<<(tot + 255) / 256, 256, 0, stream>>>(convW, wbc, NLAY * NHID, NHID, NHID);
    hipMemsetAsync(wbo, 0, (size_t)NCPAD * NHID * 2, stream);
    tot = NCLS * (NHID >> 2);
    k_cast_pad<<<(tot + 255) / 256, 256, 0, stream>>>(outW, wbo, NCLS, NHID, NHID);
  }

  // GEMM grid: 16 blocks per 8-row-tile group (XCD-pair swizzle)
  const int RT = (N + 127) / 128;
  const int ngg = ((RT + 7) / 8) * 16;

  // input layer first (so xb can be reused as CSR scratch)
  k_gemm<0><<<ngg, 256, 0, stream>>>(xb, wbi, inB, h, N, KPAD);

  // CSR build: locality-binned two-phase counting sort, hierarchical scan
  hipMemsetAsync(ccur, 0, (size_t)P * 4, stream);
  kA_scatter<<<(E + CHUNK - 1) / CHUNK, 256, 0, stream>>>(row, col, val, ccur, pb, E, P, CAP);
  kB_cnt<<<P, 256, 0, stream>>>(ccur, pb, cnt, bsum, N, CAP);
  k_scanP<<<1, 1024, 0, stream>>>(bsum, boff, ptr + N, P);
  kB_ptr<<<P, 256, 0, stream>>>(cnt, boff, ptr, N);
  kB_scatter<<<P, 256, 0, stream>>>(ccur, pb, ptr, cv, CAP);

  int nwb = (N + 3) / 4;
  for (int i = 0; i < NLAY; i++) {
    k_ln<1><<<nwb, 256, 0, stream>>>(h, lnG + i * NHID, lnB + i * NHID, t8, N);
    k_spmm<<<nwb, 256, 0, stream>>>(ptr, cv, t8, ab, N);
    if (i < NLAY - 1)
      k_gemm<1><<<ngg, 256, 0, stream>>>(ab, wbc + (size_t)i * NHID * NHID,
                                         convB + i * NHID, h, N, NHID);
    else
      k_gemm<2><<<ngg, 256, 0, stream>>>(ab, wbc + (size_t)i * NHID * NHID,
                                         convB + i * NHID, h, N, NHID);
  }

  k_ln<0><<<nwb, 256, 0, stream>>>(h, outG, outB, tb, N);
  k_ogemm<<<(N + 255) / 256, 256, 0, stream>>>(tb, wbo, outb, z, N);
}

// Round 13
// 1245.948 us; speedup vs baseline: 1.3122x; 1.0005x over previous
//
#include <hip/hip_runtime.h>
#include <stdint.h>

#define NFEAT 500
#define KPAD  512
#define NHID  256
#define NCLS  40
#define NCPAD 48
#define NLAY  5
#define BSH   8      // coarse bucket = row >> 8
#define CHUNK 8192   // edges per kA block

typedef __attribute__((ext_vector_type(8))) short short8;
typedef __attribute__((ext_vector_type(4))) float f32x4;
typedef __attribute__((ext_vector_type(2))) float f32x2;

__device__ __forceinline__ ushort f2bf(float f) {
  uint32_t u = __float_as_uint(f);
  u += 0x7fffu + ((u >> 16) & 1u);
  return (ushort)(u >> 16);
}
__device__ __forceinline__ float b2f(ushort h) {
  return __uint_as_float(((uint32_t)h) << 16);
}

// ---------------- casts (fp32 -> bf16, with K padding) ----------------
__global__ __launch_bounds__(256) void k_cast_pad(const float* __restrict__ src,
    ushort* __restrict__ dst, int rows, int scol, int dcol) {
  int id = blockIdx.x * 256 + threadIdx.x;
  int cpr = dcol >> 2;
  if (id >= rows * cpr) return;
  int r = id / cpr;
  int c = (id % cpr) * 4;
  float4 v;
  if (c + 3 < scol) {
    v = *(const float4*)(src + (size_t)r * scol + c);
  } else {
    v.x = (c + 0 < scol) ? src[(size_t)r * scol + c + 0] : 0.f;
    v.y = (c + 1 < scol) ? src[(size_t)r * scol + c + 1] : 0.f;
    v.z = (c + 2 < scol) ? src[(size_t)r * scol + c + 2] : 0.f;
    v.w = (c + 3 < scol) ? src[(size_t)r * scol + c + 3] : 0.f;
  }
  ushort4 o;
  o.x = f2bf(v.x); o.y = f2bf(v.y); o.z = f2bf(v.z); o.w = f2bf(v.w);
  *(ushort4*)(dst + (size_t)r * dcol + c) = o;
}

// ---------------- CSR build, phase A: coarse bucket scatter ----------------
__global__ __launch_bounds__(256) void kA_scatter(const int* __restrict__ row,
    const int* __restrict__ col, const float* __restrict__ val,
    int* __restrict__ ccur, int2* __restrict__ pb, int E, int P, int CAP) {
  __shared__ int lh[512];
  const int t = threadIdx.x;
  const int b0 = blockIdx.x * CHUNK;
  for (int i = t; i < P; i += 256) lh[i] = 0;
  __syncthreads();
#pragma unroll 4
  for (int i = 0; i < CHUNK / 256; i++) {
    int idx = b0 + i * 256 + t;
    if (idx < E) atomicAdd(&lh[row[idx] >> BSH], 1);
  }
  __syncthreads();
  for (int i = t; i < P; i += 256) {
    int c = lh[i];
    lh[i] = (c > 0) ? atomicAdd(&ccur[i], c) : 0;
  }
  __syncthreads();
#pragma unroll 4
  for (int i = 0; i < CHUNK / 256; i++) {
    int idx = b0 + i * 256 + t;
    if (idx < E) {
      int r = row[idx];
      int p = r >> BSH;
      int pos = atomicAdd(&lh[p], 1);
      if (pos < CAP)
        pb[(size_t)p * CAP + pos] =
            make_int2(col[idx] | ((r & 255) << 24), __float_as_int(val[idx]));
    }
  }
}

// ---------------- CSR build, phase B1: per-row counts + bucket sums ----------------
__global__ __launch_bounds__(256) void kB_cnt(const int* __restrict__ ccur,
    const int2* __restrict__ pb, int* __restrict__ cnt, int* __restrict__ bsum,
    int N, int CAP) {
  __shared__ int lc[256];
  __shared__ int ws[4];
  const int b = blockIdx.x;
  const int t = threadIdx.x;
  lc[t] = 0;
  __syncthreads();
  int cb = min(ccur[b], CAP);
  size_t base = (size_t)b * CAP;
  for (int i = t; i < cb; i += 256)
    atomicAdd(&lc[((uint32_t)pb[base + i].x) >> 24], 1);
  __syncthreads();
  int c = lc[t];
  int r = (b << BSH) + t;
  if (r < N) cnt[r] = c;
  int v = c;
  v += __shfl_xor(v, 1); v += __shfl_xor(v, 2); v += __shfl_xor(v, 4);
  v += __shfl_xor(v, 8); v += __shfl_xor(v, 16); v += __shfl_xor(v, 32);
  if ((t & 63) == 0) ws[t >> 6] = v;
  __syncthreads();
  if (t == 0) bsum[b] = ws[0] + ws[1] + ws[2] + ws[3];
}

// ---------------- CSR build: scan of bucket sums (1 block) ----------------
__global__ __launch_bounds__(1024) void k_scanP(const int* __restrict__ bsum,
    int* __restrict__ boff, int* __restrict__ ptrN, int P) {
  __shared__ int ls[1024];
  int t = threadIdx.x;
  int v = (t < P) ? bsum[t] : 0;
  ls[t] = v;
  __syncthreads();
  for (int off = 1; off < 1024; off <<= 1) {
    int u = (t >= off) ? ls[t - off] : 0;
    __syncthreads();
    ls[t] += u;
    __syncthreads();
  }
  if (t < P) boff[t] = ls[t] - v;
  if (t == 1023) *ptrN = ls[1023];
}

// ---------------- CSR build: per-bucket row-offset scan ----------------
__global__ __launch_bounds__(256) void kB_ptr(const int* __restrict__ cnt,
    const int* __restrict__ boff, int* __restrict__ ptr, int N) {
  __shared__ int ls[256];
  int b = blockIdx.x;
  int t = threadIdx.x;
  int r = (b << BSH) + t;
  int v = (r < N) ? cnt[r] : 0;
  ls[t] = v;
  __syncthreads();
  for (int off = 1; off < 256; off <<= 1) {
    int u = (t >= off) ? ls[t - off] : 0;
    __syncthreads();
    ls[t] += u;
    __syncthreads();
  }
  if (r < N) ptr[r] = boff[b] + ls[t] - v;
}

// ---------------- CSR build, phase B2: within-bucket rank scatter ----------------
__global__ __launch_bounds__(256) void kB_scatter(const int* __restrict__ ccur,
    const int2* __restrict__ pb, const int* __restrict__ ptr,
    int2* __restrict__ cv, int CAP) {
  __shared__ int rk[256];
  const int b = blockIdx.x;
  rk[threadIdx.x] = 0;
  __syncthreads();
  int cb = min(ccur[b], CAP);
  size_t base = (size_t)b * CAP;
  for (int i = threadIdx.x; i < cb; i += 256) {
    int2 p2 = pb[base + i];
    int r8 = ((uint32_t)p2.x) >> 24;
    int r = (b << BSH) + r8;
    int rank = atomicAdd(&rk[r8], 1);
    cv[ptr[r] + rank] = make_int2(p2.x & 0x00FFFFFF, p2.y);
  }
}

// ---------------- LayerNorm: bf16 h row -> normalized row ----------------
// FP8OUT=1: emit fp8 e4m3 (spmm gather payload). FP8OUT=0: emit bf16.
template<int FP8OUT>
__global__ __launch_bounds__(256) void k_ln(const ushort* __restrict__ h,
    const float* __restrict__ g, const float* __restrict__ b,
    void* __restrict__ o, int n) {
  int r = (blockIdx.x * 256 + threadIdx.x) >> 6;
  int lane = threadIdx.x & 63;
  if (r >= n) return;
  ushort4 hv = *(const ushort4*)(h + (size_t)r * NHID + lane * 4);
  float v0 = b2f(hv.x), v1 = b2f(hv.y), v2 = b2f(hv.z), v3 = b2f(hv.w);
  float s = v0 + v1 + v2 + v3;
  s += __shfl_xor(s, 1); s += __shfl_xor(s, 2); s += __shfl_xor(s, 4);
  s += __shfl_xor(s, 8); s += __shfl_xor(s, 16); s += __shfl_xor(s, 32);
  float mu = s * (1.f / NHID);
  float d0 = v0 - mu, d1 = v1 - mu, d2 = v2 - mu, d3 = v3 - mu;
  float q = d0 * d0 + d1 * d1 + d2 * d2 + d3 * d3;
  q += __shfl_xor(q, 1); q += __shfl_xor(q, 2); q += __shfl_xor(q, 4);
  q += __shfl_xor(q, 8); q += __shfl_xor(q, 16); q += __shfl_xor(q, 32);
  float rs = rsqrtf(q * (1.f / NHID) + 1e-5f);
  float4 gv = *(const float4*)(g + lane * 4);
  float4 bv = *(const float4*)(b + lane * 4);
  float o0 = d0 * rs * gv.x + bv.x;
  float o1 = d1 * rs * gv.y + bv.y;
  float o2 = d2 * rs * gv.z + bv.z;
  float o3 = d3 * rs * gv.w + bv.w;
  if (FP8OUT) {
    int w = 0;
    w = __builtin_amdgcn_cvt_pk_fp8_f32(o0, o1, w, false);
    w = __builtin_amdgcn_cvt_pk_fp8_f32(o2, o3, w, true);
    ((uint32_t*)o)[(size_t)r * 64 + lane] = (uint32_t)w;
  } else {
    ushort4 t;
    t.x = f2bf(o0); t.y = f2bf(o1); t.z = f2bf(o2); t.w = f2bf(o3);
    *(ushort4*)((ushort*)o + (size_t)r * NHID + lane * 4) = t;
  }
}

// ---------------- SpMM: agg[i] = sum_e val[e] * t8[col[e]]  (fp8 gather) ----------------
// One wave/row; 4 edges/iter (quarter lane>>4), 16B/lane uint4 gathers (16 lanes
// span the 256B fp8 row), unroll 8 for deep MLP. Packed pk_fma accumulate.
__global__ __launch_bounds__(256) void k_spmm(const int* __restrict__ ptr,
    const int2* __restrict__ cv, const uint32_t* __restrict__ t8,
    ushort* __restrict__ agg, int n) {
  int r = (blockIdx.x * 256 + threadIdx.x) >> 6;
  int lane = threadIdx.x & 63;
  if (r >= n) return;
  int s = ptr[r], e = ptr[r + 1];
  int cnt = e - s;
  int q = lane >> 4;
  int seg = lane & 15;
  f32x2 acc2[8];
#pragma unroll
  for (int j = 0; j < 8; j++) acc2[j] = (f32x2){0.f, 0.f};

  for (int base = 0; base < cnt; base += 64) {
    int idx = s + base + lane;
    int ec = 0; float ev = 0.f;
    if (idx < e) {
      int2 p2 = cv[idx];
      ec = p2.x;
      ev = __uint_as_float((uint32_t)p2.y);
    }
    int lim = min(64, cnt - base);
#pragma unroll 8
    for (int i = 0; i < lim; i += 4) {
      int a = i + q;                    // a <= 63 always
      int c = __shfl(ec, a);
      float v = __shfl(ev, a);          // 0 for out-of-range edges
      f32x2 vv = {v, v};
      uint4 tv = *(const uint4*)(t8 + (size_t)c * 64 + seg * 4);
      f32x2 p;
      p = __builtin_amdgcn_cvt_pk_f32_fp8(tv.x, false);
      acc2[0] = __builtin_elementwise_fma(p, vv, acc2[0]);
      p = __builtin_amdgcn_cvt_pk_f32_fp8(tv.x, true);
      acc2[1] = __builtin_elementwise_fma(p, vv, acc2[1]);
      p = __builtin_amdgcn_cvt_pk_f32_fp8(tv.y, false);
      acc2[2] = __builtin_elementwise_fma(p, vv, acc2[2]);
      p = __builtin_amdgcn_cvt_pk_f32_fp8(tv.y, true);
      acc2[3] = __builtin_elementwise_fma(p, vv, acc2[3]);
      p = __builtin_amdgcn_cvt_pk_f32_fp8(tv.z, false);
      acc2[4] = __builtin_elementwise_fma(p, vv, acc2[4]);
      p = __builtin_amdgcn_cvt_pk_f32_fp8(tv.z, true);
      acc2[5] = __builtin_elementwise_fma(p, vv, acc2[5]);
      p = __builtin_amdgcn_cvt_pk_f32_fp8(tv.w, false);
      acc2[6] = __builtin_elementwise_fma(p, vv, acc2[6]);
      p = __builtin_amdgcn_cvt_pk_f32_fp8(tv.w, true);
      acc2[7] = __builtin_elementwise_fma(p, vv, acc2[7]);
    }
  }

  float accs[16];
#pragma unroll
  for (int j = 0; j < 8; j++) { accs[2 * j] = acc2[j][0]; accs[2 * j + 1] = acc2[j][1]; }
#pragma unroll
  for (int j = 0; j < 16; j++) {
    accs[j] += __shfl_xor(accs[j], 16);
    accs[j] += __shfl_xor(accs[j], 32);
  }
  if (q == 0) {
    short8 o0, o1;
#pragma unroll
    for (int j = 0; j < 8; j++) { o0[j] = (short)f2bf(accs[j]); o1[j] = (short)f2bf(accs[8 + j]); }
    *(short8*)(agg + (size_t)r * NHID + seg * 16) = o0;
    *(short8*)(agg + (size_t)r * NHID + seg * 16 + 8) = o1;
  }
}

// ---------------- MFMA GEMM: C = A(MxK,bf16) @ B(NxK,bf16)^T, fused epilogue ----------------
// H is bf16. MODE 0: H = relu(C+bias); 1: H += relu(C+bias); 2: H += C+bias
// 1-D grid with XCD-pair swizzle: ids o and o+8 in each 16-group (same XCD under
// round-robin) are (bcol0, bcol1) of the same 128 A-rows -> A is L2-hot.
template<int MODE>
__global__ __launch_bounds__(256) void k_gemm(const ushort* __restrict__ A,
    const ushort* __restrict__ B, const float* __restrict__ bias,
    ushort* __restrict__ H, int M, int K) {
  const int RT = (M + 127) >> 7;
  const int g = blockIdx.x >> 4;
  const int o = blockIdx.x & 15;
  const int rowi = g * 8 + (o & 7);
  if (rowi >= RT) return;
  const int brow = rowi * 128;
  const int bcol = (o >> 3) * 128;
  __shared__ ushort As[128 * 32];
  __shared__ ushort Bs[128 * 32];
  const int t = threadIdx.x;
  const int lane = t & 63;
  const int wid = t >> 6;
  const int wr = (wid >> 1) * 64;
  const int wc = (wid & 1) * 64;
  const int l15 = lane & 15, hi = lane >> 4;
  const f32x4 z4 = {0.f, 0.f, 0.f, 0.f};
  f32x4 acc[4][4];
  for (int m = 0; m < 4; m++)
    for (int n = 0; n < 4; n++) acc[m][n] = z4;

  for (int k0 = 0; k0 < K; k0 += 32) {
    __syncthreads();
#pragma unroll
    for (int c = 0; c < 2; c++) {
      int s = c * 256 + t;
      int r = s >> 2;
      int kk = (s & 3) * 8;
      int gr = brow + r; gr = gr < M ? gr : M - 1;
      const ushort* ga = A + (size_t)gr * K + (k0 + kk);
      __builtin_amdgcn_global_load_lds((const __attribute__((address_space(1))) void*)ga,
          (__attribute__((address_space(3))) void*)(As + s * 8), 16, 0, 0);
      const ushort* gb = B + (size_t)(bcol + r) * K + (k0 + kk);
      __builtin_amdgcn_global_load_lds((const __attribute__((address_space(1))) void*)gb,
          (__attribute__((address_space(3))) void*)(Bs + s * 8), 16, 0, 0);
    }
    __syncthreads();
    short8 af[4], bf[4];
#pragma unroll
    for (int m = 0; m < 4; m++)
      af[m] = *(const short8*)(As + (wr + m * 16 + l15) * 32 + hi * 8);
#pragma unroll
    for (int n = 0; n < 4; n++)
      bf[n] = *(const short8*)(Bs + (wc + n * 16 + l15) * 32 + hi * 8);
#pragma unroll
    for (int m = 0; m < 4; m++)
#pragma unroll
      for (int n = 0; n < 4; n++)
        acc[m][n] = __builtin_amdgcn_mfma_f32_16x16x32_bf16(af[m], bf[n], acc[m][n], 0, 0, 0);
  }

#pragma unroll
  for (int m = 0; m < 4; m++) {
    int gr0 = brow + wr + m * 16 + hi * 4;
#pragma unroll
    for (int n = 0; n < 4; n++) {
      int gc = bcol + wc + n * 16 + l15;
      float bv = bias[gc];
#pragma unroll
      for (int j = 0; j < 4; j++) {
        int gr = gr0 + j;
        if (gr < M) {
          size_t idx = (size_t)gr * NHID + gc;
          float v = acc[m][n][j] + bv;
          if (MODE == 0)      H[idx] = f2bf(fmaxf(v, 0.f));
          else if (MODE == 1) H[idx] = f2bf(b2f(H[idx]) + fmaxf(v, 0.f));
          else                H[idx] = f2bf(b2f(H[idx]) + v);
        }
      }
    }
  }
}

// ---------------- output GEMM: z = Anorm @ Wo^T + ob  (skinny N=40, MFMA) ----------------
__global__ __launch_bounds__(256) void k_ogemm(const ushort* __restrict__ A,
    const ushort* __restrict__ Bw, const float* __restrict__ ob,
    float* __restrict__ z, int M) {
  __shared__ ushort As[256 * 32];
  __shared__ ushort Bs[NCPAD * 264];
  const int t = threadIdx.x;
  const int lane = t & 63;
  const int wid = t >> 6;
  const int brow = blockIdx.x * 256;
  const int wr = wid * 64;
  const int l15 = lane & 15, hi = lane >> 4;
  const f32x4 z4 = {0.f, 0.f, 0.f, 0.f};
  f32x4 acc[4][3];
#pragma unroll
  for (int m = 0; m < 4; m++)
#pragma unroll
    for (int n = 0; n < 3; n++) acc[m][n] = z4;

  for (int i = t; i < NCPAD * 33; i += 256) {
    int r = i / 33, cc = i % 33;
    if (cc < 32)
      *(short8*)(Bs + r * 264 + cc * 8) = *(const short8*)(Bw + r * 256 + cc * 8);
  }

  for (int k0 = 0; k0 < 256; k0 += 32) {
    __syncthreads();
#pragma unroll
    for (int c = 0; c < 4; c++) {
      int s = c * 256 + t;
      int r = s >> 2;
      int kk = (s & 3) * 8;
      int gr = brow + r; gr = gr < M ? gr : M - 1;
      const ushort* ga = A + (size_t)gr * NHID + (k0 + kk);
      __builtin_amdgcn_global_load_lds((const __attribute__((address_space(1))) void*)ga,
          (__attribute__((address_space(3))) void*)(As + s * 8), 16, 0, 0);
    }
    __syncthreads();
    short8 af[4], bf[3];
#pragma unroll
    for (int m = 0; m < 4; m++)
      af[m] = *(const short8*)(As + (wr + m * 16 + l15) * 32 + hi * 8);
#pragma unroll
    for (int n = 0; n < 3; n++)
      bf[n] = *(const short8*)(Bs + (n * 16 + l15) * 264 + k0 + hi * 8);
#pragma unroll
    for (int m = 0; m < 4; m++)
#pragma unroll
      for (int n = 0; n < 3; n++)
        acc[m][n] = __builtin_amdgcn_mfma_f32_16x16x32_bf16(af[m], bf[n], acc[m][n], 0, 0, 0);
  }

#pragma unroll
  for (int m = 0; m < 4; m++) {
    int gr0 = brow + wr + m * 16 + hi * 4;
#pragma unroll
    for (int n = 0; n < 3; n++) {
      int gc = n * 16 + l15;
      if (gc < NCLS) {
        float bv = ob[gc];
#pragma unroll
        for (int j = 0; j < 4; j++) {
          int gr = gr0 + j;
          if (gr < M) z[(size_t)gr * NCLS + gc] = acc[m][n][j] + bv;
        }
      }
    }
  }
}

extern "C" void kernel_launch(void* const* d_in, const int* in_sizes, int n_in,
                              void* d_out, int out_size, void* d_ws, size_t ws_size,
                              hipStream_t stream) {
  const float* x     = (const float*)d_in[0];
  const int*   row   = (const int*)d_in[1];
  const int*   col   = (const int*)d_in[2];
  const float* val   = (const float*)d_in[3];
  const float* inW   = (const float*)d_in[4];
  const float* inB   = (const float*)d_in[5];
  const float* convW = (const float*)d_in[6];
  const float* convB = (const float*)d_in[7];
  const float* lnG   = (const float*)d_in[8];
  const float* lnB   = (const float*)d_in[9];
  const float* outG  = (const float*)d_in[10];
  const float* outB  = (const float*)d_in[11];
  const float* outW  = (const float*)d_in[12];
  const float* outb  = (const float*)d_in[13];
  const int N = in_sizes[0] / NFEAT;
  const int E = in_sizes[1];
  float* z = (float*)d_out;

  const int P   = (N + 255) >> BSH;
  const int CAP = ((((E + P - 1) / P) * 5 / 4 + 256) + 15) & ~15;

  char* wsp = (char*)d_ws;
  size_t off = 0;
  auto alloc = [&](size_t bytes) {
    void* p = wsp + off;
    off += (bytes + 255) & ~(size_t)255;
    return p;
  };
  ushort*   h   = (ushort*)alloc((size_t)N * NHID * 2);   // bf16 residual stream
  ushort*   tb  = (ushort*)alloc((size_t)N * NHID * 2);
  ushort*   ab  = (ushort*)alloc((size_t)N * NHID * 2);
  uint32_t* t8  = (uint32_t*)alloc((size_t)N * 64 * 4);   // fp8 LN output (256B/row)
  ushort*   xb  = (ushort*)alloc((size_t)N * KPAD * 2);   // also CSR scratch after input gemm
  ushort*   wbi = (ushort*)alloc((size_t)NHID * KPAD * 2);
  ushort*   wbc = (ushort*)alloc((size_t)NLAY * NHID * NHID * 2);
  ushort*   wbo = (ushort*)alloc((size_t)NCPAD * NHID * 2);
  int*   cnt  = (int*)alloc((size_t)N * 4);
  int*   ptr  = (int*)alloc((size_t)(N + 1) * 4);
  int*   ccur = (int*)alloc((size_t)P * 4);
  int*   bsum = (int*)alloc((size_t)P * 4);
  int*   boff = (int*)alloc((size_t)P * 4);
  int2*  cv   = (int2*)alloc((size_t)E * 8);
  int2*  pb   = (int2*)xb;   // aliases xb (dead after input gemm)

  // bf16 casts
  {
    int tot = N * (KPAD >> 2);
    k_cast_pad<<<(tot + 255) / 256, 256, 0, stream>>>(x, xb, N, NFEAT, KPAD);
    tot = NHID * (KPAD >> 2);
    k_cast_pad<<<(tot + 255) / 256, 256, 0, stream>>>(inW, wbi, NHID, NFEAT, KPAD);
    tot = NLAY * NHID * (NHID >> 2);
    k_cast_pad<<<(tot + 255) / 256, 256, 0, stream>>>(convW, wbc, NLAY * NHID, NHID, NHID);
    hipMemsetAsync(wbo, 0, (size_t)NCPAD * NHID * 2, stream);
    tot = NCLS * (NHID >> 2);
    k_cast_pad<<<(tot + 255) / 256, 256, 0, stream>>>(outW, wbo, NCLS, NHID, NHID);
  }

  // GEMM grid: 16 blocks per 8-row-tile group (XCD-pair swizzle)
  const int RT = (N + 127) / 128;
  const int ngg = ((RT + 7) / 8) * 16;

  // input layer first (so xb can be reused as CSR scratch)
  k_gemm<0><<<ngg, 256, 0, stream>>>(xb, wbi, inB, h, N, KPAD);

  // CSR build: locality-binned two-phase counting sort, hierarchical scan
  hipMemsetAsync(ccur, 0, (size_t)P * 4, stream);
  kA_scatter<<<(E + CHUNK - 1) / CHUNK, 256, 0, stream>>>(row, col, val, ccur, pb, E, P, CAP);
  kB_cnt<<<P, 256, 0, stream>>>(ccur, pb, cnt, bsum, N, CAP);
  k_scanP<<<1, 1024, 0, stream>>>(bsum, boff, ptr + N, P);
  kB_ptr<<<P, 256, 0, stream>>>(cnt, boff, ptr, N);
  kB_scatter<<<P, 256, 0, stream>>>(ccur, pb, ptr, cv, CAP);

  int nwb = (N + 3) / 4;
  for (int i = 0; i < NLAY; i++) {
    k_ln<1><<<nwb, 256, 0, stream>>>(h, lnG + i * NHID, lnB + i * NHID, t8, N);
    k_spmm<<<nwb, 256, 0, stream>>>(ptr, cv, t8, ab, N);
    if (i < NLAY - 1)
      k_gemm<1><<<ngg, 256, 0, stream>>>(ab, wbc + (size_t)i * NHID * NHID,
                                         convB + i * NHID, h, N, NHID);
    else
      k_gemm<2><<<ngg, 256, 0, stream>>>(ab, wbc + (size_t)i * NHID * NHID,
                                         convB + i * NHID, h, N, NHID);
  }

  k_ln<0><<<nwb, 256, 0, stream>>>(h, outG, outB, tb, N);
  k_ogemm<<<(N + 255) / 256, 256, 0, stream>>>(tb, wbo, outb, z, N);
}